// Round 2
// baseline (5252.218 us; speedup 1.0000x reference)
//
#include <hip/hip_runtime.h>
#include <hip/hip_bf16.h>
#include <cstdint>
#include <cstddef>

#define EPS_BN 1e-5f

static inline int idiv(int a, int b) { return (a + b - 1) / b; }

__device__ __forceinline__ float ldv(const float* p) { return *p; }
__device__ __forceinline__ float ldv(const __hip_bfloat16* p) { return __bfloat162float(*p); }
__device__ __forceinline__ void stv(float* p, float v) { *p = v; }
__device__ __forceinline__ void stv(__hip_bfloat16* p, float v) { *p = __float2bfloat16(v); }

// ---------------- CSR build ----------------
__global__ void cnt_kernel(const int* __restrict__ ei, int* __restrict__ cnt, int E) {
  int e = blockIdx.x * 256 + threadIdx.x;
  if (e < E) atomicAdd(&cnt[ei[E + e]], 1);
}

__global__ __launch_bounds__(1024) void scan_kernel(const int* __restrict__ cnt,
                                                    int* __restrict__ row_ptr,
                                                    int* __restrict__ cursor, int n) {
  __shared__ int ps[1024];
  int t = threadIdx.x;
  int chunk = (n + 1023) >> 10;
  int lo = t * chunk; if (lo > n) lo = n;
  int hi = lo + chunk; if (hi > n) hi = n;
  int s = 0;
  for (int i = lo; i < hi; ++i) s += cnt[i];
  ps[t] = s;
  __syncthreads();
  for (int off = 1; off < 1024; off <<= 1) {
    int v = (t >= off) ? ps[t - off] : 0;
    __syncthreads();
    ps[t] += v;
    __syncthreads();
  }
  int run = (t > 0) ? ps[t - 1] : 0;
  for (int i = lo; i < hi; ++i) { row_ptr[i] = run; cursor[i] = run; run += cnt[i]; }
  if (t == 1023) row_ptr[n] = ps[1023];
}

__global__ void fill_kernel(const int* __restrict__ ei, int* __restrict__ cursor,
                            int* __restrict__ col_idx, int E) {
  int e = blockIdx.x * 256 + threadIdx.x;
  if (e < E) {
    int d = ei[E + e];
    int p = atomicAdd(&cursor[d], 1);
    col_idx[p] = ei[e];
  }
}

// ---------------- input projection: out[n][128] = X[n][D] @ W.T + b ----------------
template<int D, typename T>
__global__ __launch_bounds__(256) void proj_kernel(const float* __restrict__ X,
    const float* __restrict__ W, const float* __restrict__ bias,
    T* __restrict__ out, int n) {
  __shared__ float wT[D][129];
  int tid = threadIdx.x, lane = tid & 63, wv = tid >> 6;
  for (int idx = tid; idx < 128 * D; idx += 256) {
    int k = idx % D, j = idx / D;
    wT[k][j] = W[idx];  // coalesced read of W[j][k]
  }
  __syncthreads();
  float b0 = bias[lane], b1 = bias[lane + 64];
  for (int row = blockIdx.x * 4 + wv; row < n; row += gridDim.x * 4) {
    const float4* xr = (const float4*)(X + (size_t)row * D);
    float a0 = b0, a1 = b1;
#pragma unroll
    for (int k4 = 0; k4 < D / 4; ++k4) {
      float4 x = xr[k4];
      int k = k4 * 4;
      a0 += x.x * wT[k][lane]      + x.y * wT[k + 1][lane]
          + x.z * wT[k + 2][lane]  + x.w * wT[k + 3][lane];
      a1 += x.x * wT[k][lane + 64]     + x.y * wT[k + 1][lane + 64]
          + x.z * wT[k + 2][lane + 64] + x.w * wT[k + 3][lane + 64];
    }
    stv(&out[(size_t)row * 128 + lane], a0);
    stv(&out[(size_t)row * 128 + 64 + lane], a1);
  }
}

// ---------------- fused SAGE: gather-mean + GEMMs + bias + L2-norm [+accum] ----
// out[row][0:DOUT] = l2norm( mean_{nbrs}(xsrc) @ Wl.T + bl + xd[row] @ Wr.T )
template<int DOUT, bool ACCUM, typename T>
__global__ __launch_bounds__(256) void sage_fused_kernel(
    const int* __restrict__ row_ptr, const int* __restrict__ col_idx,
    const T* __restrict__ xsrc, const T* __restrict__ xd,
    const float* __restrict__ Wl, const float* __restrict__ bl,
    const float* __restrict__ Wr, T* __restrict__ out, int n) {
  constexpr int NCOL = DOUT / 64;
  __shared__ float am[32][128];   // mean-aggregated neighbors (broadcast reads)
  __shared__ float ax[32][128];   // dst features
  __shared__ float wl_t[16][DOUT + 1];
  __shared__ float wr_t[16][DOUT + 1];
  const int tid = threadIdx.x;
  const int lane = tid & 63;
  const int wv = tid >> 6;
  const int base = blockIdx.x * 32;

  // ---- gather phase: each wave handles rows wv, wv+4, ... (8 rows) ----
  for (int r = wv; r < 32; r += 4) {
    int row = base + r;
    float a0 = 0.f, a1 = 0.f, x0 = 0.f, x1 = 0.f;
    if (row < n) {
      int beg = row_ptr[row], end = row_ptr[row + 1];
      for (int p = beg; p < end; ++p) {
        const T* xr = xsrc + (size_t)col_idx[p] * 128;
        a0 += ldv(xr + lane);
        a1 += ldv(xr + lane + 64);
      }
      float rc = (end > beg) ? 1.f / (float)(end - beg) : 0.f;
      a0 *= rc; a1 *= rc;
      const T* xr = xd + (size_t)row * 128;
      x0 = ldv(xr + lane);
      x1 = ldv(xr + lane + 64);
    }
    am[r][lane] = a0; am[r][lane + 64] = a1;
    ax[r][lane] = x0; ax[r][lane + 64] = x1;
  }

  float acc[8][NCOL];
#pragma unroll
  for (int r = 0; r < 8; ++r)
#pragma unroll
    for (int c = 0; c < NCOL; ++c) acc[r][c] = bl[lane + c * 64];

  // ---- K-loop: 8 tiles of 16 ----
  for (int k0 = 0; k0 < 128; k0 += 16) {
    __syncthreads();  // gather/previous-tile reads done before restaging W
    for (int idx = tid; idx < 16 * DOUT; idx += 256) {
      int kk = idx & 15, j = idx >> 4;
      wl_t[kk][j] = Wl[j * 128 + k0 + kk];
      wr_t[kk][j] = Wr[j * 128 + k0 + kk];
    }
    __syncthreads();
#pragma unroll
    for (int r = 0; r < 8; ++r) {
      int rr = wv * 8 + r;
      const float4* amp = (const float4*)&am[rr][k0];
      const float4* axp = (const float4*)&ax[rr][k0];
#pragma unroll
      for (int q = 0; q < 4; ++q) {
        float4 m4 = amp[q], x4 = axp[q];
        float mv[4] = {m4.x, m4.y, m4.z, m4.w};
        float xv[4] = {x4.x, x4.y, x4.z, x4.w};
#pragma unroll
        for (int s = 0; s < 4; ++s) {
          int kk = q * 4 + s;
          acc[r][0] += mv[s] * wl_t[kk][lane] + xv[s] * wr_t[kk][lane];
          if (NCOL == 2)
            acc[r][1] += mv[s] * wl_t[kk][lane + 64] + xv[s] * wr_t[kk][lane + 64];
        }
      }
    }
  }

  // ---- epilogue: row L2-norm, store / accumulate ----
#pragma unroll
  for (int r = 0; r < 8; ++r) {
    int row = base + wv * 8 + r;
    float ss = acc[r][0] * acc[r][0];
    if (NCOL == 2) ss += acc[r][1] * acc[r][1];
#pragma unroll
    for (int off = 32; off; off >>= 1) ss += __shfl_xor(ss, off);
    float rn = 1.0f / fmaxf(sqrtf(ss), 1e-12f);
    if (row < n) {
      T* op = out + (size_t)row * DOUT;
      if (ACCUM) {
        stv(op + lane, ldv(op + lane) + acc[r][0] * rn);
        if (NCOL == 2) stv(op + 64 + lane, ldv(op + 64 + lane) + acc[r][1] * rn);
      } else {
        stv(op + lane, acc[r][0] * rn);
        if (NCOL == 2) stv(op + 64 + lane, acc[r][1] * rn);
      }
    }
  }
}

// ---------------- BatchNorm (training-mode batch stats) ----------------
template<int C, typename T>
__global__ __launch_bounds__(256) void bn_stats_kernel(const T* __restrict__ x,
    float* __restrict__ stats, int n) {
  constexpr int RPB = 256 / C;
  int c = threadIdx.x % C;
  float s = 0.f, ss = 0.f;
  for (int r = blockIdx.x * RPB + threadIdx.x / C; r < n; r += gridDim.x * RPB) {
    float v = ldv(x + (size_t)r * C + c);
    s += v; ss += v * v;
  }
  atomicAdd(&stats[c], s);
  atomicAdd(&stats[C + c], ss);
}

template<int C, bool RELU, typename T>
__global__ __launch_bounds__(256) void bn_apply_kernel(T* __restrict__ x,
    const float* __restrict__ stats, const float* __restrict__ g,
    const float* __restrict__ b, int n) {
  size_t i = (size_t)blockIdx.x * 256 + threadIdx.x;
  size_t total = (size_t)n * C;
  if (i >= total) return;
  int c = (int)(i & (C - 1));
  float rn = 1.f / (float)n;
  float mu = stats[c] * rn;
  float var = stats[C + c] * rn - mu * mu;
  float v = (ldv(&x[i]) - mu) * rsqrtf(var + EPS_BN) * g[c] + b[c];
  if (RELU) v = fmaxf(v, 0.f);
  stv(&x[i], v);
}

// ---------------- classifier: out[n] = relu(X @ W1.T + b1) @ W2.T + b2 ------
template<typename T>
__global__ __launch_bounds__(256) void clf_kernel(const T* __restrict__ X,
    const float* __restrict__ W1, const float* __restrict__ b1,
    const float* __restrict__ W2, const float* __restrict__ b2,
    float* __restrict__ out, int n) {
  __shared__ float w1T[64][65];
  __shared__ float w2s[64];
  int tid = threadIdx.x, lane = tid & 63, wv = tid >> 6;
  for (int idx = tid; idx < 4096; idx += 256) {
    int k = idx & 63, j = idx >> 6;
    w1T[k][j] = W1[idx];
  }
  if (tid < 64) w2s[tid] = W2[tid];
  __syncthreads();
  float bb = b1[lane];
  float b2v = b2[0];
  for (int row = blockIdx.x * 4 + wv; row < n; row += gridDim.x * 4) {
    const T* xr = X + (size_t)row * 64;
    float acc = bb;
#pragma unroll
    for (int k = 0; k < 64; ++k) acc += ldv(xr + k) * w1T[k][lane];
    float h = fmaxf(acc, 0.f) * w2s[lane];
#pragma unroll
    for (int off = 32; off; off >>= 1) h += __shfl_xor(h, off);
    if (lane == 0) out[row] = h + b2v;
  }
}

// ---------------- one hetero layer ----------------
template<int DO, bool RELU, typename T>
static void run_layer(const float* Wl, const float* bl, const float* Wr,
                      const float* g, const float* b,
                      const T* xa, const T* xm, T* oa, T* om, float* STATS,
                      const int* rp_p, const int* ci_p,
                      const int* rp_r, const int* ci_r,
                      const int* rp_t, const int* ci_t,
                      int NA, int NM, hipStream_t stream) {
  // pays: account -> merchant
  sage_fused_kernel<DO, false, T><<<idiv(NM, 32), 256, 0, stream>>>(
      rp_p, ci_p, xa, xm, Wl, bl, Wr, om, NM);
  // rev_pays: merchant -> account
  sage_fused_kernel<DO, false, T><<<idiv(NA, 32), 256, 0, stream>>>(
      rp_r, ci_r, xm, xa, Wl + DO * 128, bl + DO, Wr + DO * 128, oa, NA);
  // transfer: account -> account (accumulate)
  sage_fused_kernel<DO, true, T><<<idiv(NA, 32), 256, 0, stream>>>(
      rp_t, ci_t, xa, xa, Wl + 2 * DO * 128, bl + 2 * DO, Wr + 2 * DO * 128, oa, NA);
  // BN account
  hipMemsetAsync(STATS, 0, 2 * DO * sizeof(float), stream);
  bn_stats_kernel<DO, T><<<1024, 256, 0, stream>>>(oa, STATS, NA);
  bn_apply_kernel<DO, RELU, T><<<idiv(NA * DO, 256), 256, 0, stream>>>(oa, STATS, g, b, NA);
  // BN merchant
  hipMemsetAsync(STATS, 0, 2 * DO * sizeof(float), stream);
  bn_stats_kernel<DO, T><<<1024, 256, 0, stream>>>(om, STATS, NM);
  bn_apply_kernel<DO, RELU, T><<<idiv(NM * DO, 256), 256, 0, stream>>>(om, STATS, g + DO, b + DO, NM);
}

static size_t ws_need(int NA, int NM, int E, size_t esz) {
  size_t acts = ((size_t)2 * NA * 128 + (size_t)2 * NM * 128) * esz;
  acts = (acts + 15) & ~(size_t)15;
  size_t stats = 256 * 4;
  size_t ints = ((size_t)(NM + 1) + NM + E + 2 * ((size_t)(NA + 1) + NA + E) + NA) * 4;
  return acts + stats + ints + 64;
}

template<typename T>
static void run_all(void* const* d_in, float* d_out, void* d_ws,
                    int NA, int NM, int E, hipStream_t stream) {
  const float* x_acc = (const float*)d_in[0];
  const float* x_mer = (const float*)d_in[1];
  const int* ei_pays = (const int*)d_in[2];
  const int* ei_rev  = (const int*)d_in[3];
  const int* ei_tr   = (const int*)d_in[4];
  const float* pWa = (const float*)d_in[5];
  const float* pba = (const float*)d_in[6];
  const float* pWm = (const float*)d_in[7];
  const float* pbm = (const float*)d_in[8];
  const float* Wl[3]  = {(const float*)d_in[9],  (const float*)d_in[12], (const float*)d_in[15]};
  const float* blp[3] = {(const float*)d_in[10], (const float*)d_in[13], (const float*)d_in[16]};
  const float* Wr[3]  = {(const float*)d_in[11], (const float*)d_in[14], (const float*)d_in[17]};
  const float* bng[3] = {(const float*)d_in[18], (const float*)d_in[20], (const float*)d_in[22]};
  const float* bnb[3] = {(const float*)d_in[19], (const float*)d_in[21], (const float*)d_in[23]};
  const float* cW1 = (const float*)d_in[24];
  const float* cb1 = (const float*)d_in[25];
  const float* cW2 = (const float*)d_in[26];
  const float* cb2 = (const float*)d_in[27];

  char* p = (char*)d_ws;
  T* A0 = (T*)p; p += (size_t)NA * 128 * sizeof(T);
  T* A1 = (T*)p; p += (size_t)NA * 128 * sizeof(T);
  T* M0 = (T*)p; p += (size_t)NM * 128 * sizeof(T);
  T* M1 = (T*)p; p += (size_t)NM * 128 * sizeof(T);
  p = (char*)(((uintptr_t)p + 15) & ~(uintptr_t)15);
  float* STATS = (float*)p; p += 256 * 4;
  int* rp_p  = (int*)p; p += ((size_t)NM + 1) * 4;
  int* cur_p = (int*)p; p += (size_t)NM * 4;
  int* ci_p  = (int*)p; p += (size_t)E * 4;
  int* rp_r  = (int*)p; p += ((size_t)NA + 1) * 4;
  int* cur_r = (int*)p; p += (size_t)NA * 4;
  int* ci_r  = (int*)p; p += (size_t)E * 4;
  int* rp_t  = (int*)p; p += ((size_t)NA + 1) * 4;
  int* cur_t = (int*)p; p += (size_t)NA * 4;
  int* ci_t  = (int*)p; p += (size_t)E * 4;
  int* icnt  = (int*)p; p += (size_t)NA * 4;

  // ---- CSR builds (edges identical across layers: build once) ----
  struct ET { const int* ei; int nd; int* rp; int* cur; int* ci; };
  ET et[3] = {
      {ei_pays, NM, rp_p, cur_p, ci_p},
      {ei_rev,  NA, rp_r, cur_r, ci_r},
      {ei_tr,   NA, rp_t, cur_t, ci_t},
  };
  for (int t = 0; t < 3; ++t) {
    hipMemsetAsync(icnt, 0, (size_t)et[t].nd * sizeof(int), stream);
    cnt_kernel<<<idiv(E, 256), 256, 0, stream>>>(et[t].ei, icnt, E);
    scan_kernel<<<1, 1024, 0, stream>>>(icnt, et[t].rp, et[t].cur, et[t].nd);
    fill_kernel<<<idiv(E, 256), 256, 0, stream>>>(et[t].ei, et[t].cur, et[t].ci, E);
  }

  // ---- input projections ----
  proj_kernel<64, T><<<4096, 256, 0, stream>>>(x_acc, pWa, pba, A0, NA);
  proj_kernel<32, T><<<4096, 256, 0, stream>>>(x_mer, pWm, pbm, M0, NM);

  // ---- 3 hetero layers ----
  T *xa = A0, *xm = M0, *oa = A1, *om = M1;
  run_layer<128, true, T>(Wl[0], blp[0], Wr[0], bng[0], bnb[0], xa, xm, oa, om, STATS,
                          rp_p, ci_p, rp_r, ci_r, rp_t, ci_t, NA, NM, stream);
  { T* t = xa; xa = oa; oa = t; t = xm; xm = om; om = t; }
  run_layer<128, true, T>(Wl[1], blp[1], Wr[1], bng[1], bnb[1], xa, xm, oa, om, STATS,
                          rp_p, ci_p, rp_r, ci_r, rp_t, ci_t, NA, NM, stream);
  { T* t = xa; xa = oa; oa = t; t = xm; xm = om; om = t; }
  run_layer<64, false, T>(Wl[2], blp[2], Wr[2], bng[2], bnb[2], xa, xm, oa, om, STATS,
                          rp_p, ci_p, rp_r, ci_r, rp_t, ci_t, NA, NM, stream);
  { T* t = xa; xa = oa; oa = t; t = xm; xm = om; om = t; }

  // ---- classifier head on accounts ----
  clf_kernel<T><<<4096, 256, 0, stream>>>(xa, cW1, cb1, cW2, cb2, d_out, NA);
}

extern "C" void kernel_launch(void* const* d_in, const int* in_sizes, int n_in,
                              void* d_out, int out_size, void* d_ws, size_t ws_size,
                              hipStream_t stream) {
  const int NA = in_sizes[0] / 64;   // 200000
  const int NM = in_sizes[1] / 32;   // 100000
  const int E  = in_sizes[2] / 2;    // 500000

  if (ws_size >= ws_need(NA, NM, E, sizeof(float))) {
    run_all<float>(d_in, (float*)d_out, d_ws, NA, NM, E, stream);
  } else if (ws_size >= ws_need(NA, NM, E, sizeof(__hip_bfloat16))) {
    run_all<__hip_bfloat16>(d_in, (float*)d_out, d_ws, NA, NM, E, stream);
  }
  // else: insufficient scratch — leave output untouched (signals ws < 164MB)
}

// Round 3
// 4105.606 us; speedup vs baseline: 1.2793x; 1.2793x over previous
//
#include <hip/hip_runtime.h>
#include <hip/hip_bf16.h>
#include <cstdint>
#include <cstddef>

#define EPS_BN 1e-5f

static inline int idiv(int a, int b) { return (a + b - 1) / b; }

__device__ __forceinline__ float ldv(const float* p) { return *p; }
__device__ __forceinline__ float ldv(const __hip_bfloat16* p) { return __bfloat162float(*p); }
__device__ __forceinline__ void stv(float* p, float v) { *p = v; }
__device__ __forceinline__ void stv(__hip_bfloat16* p, float v) { *p = __float2bfloat16(v); }

// load elements {2*lane, 2*lane+1} of a 128-wide row as fp32
__device__ __forceinline__ void load2(const float* row, int lane, float& lo, float& hi) {
  float2 v = ((const float2*)row)[lane];
  lo = v.x; hi = v.y;
}
__device__ __forceinline__ void load2(const __hip_bfloat16* row, int lane, float& lo, float& hi) {
  unsigned int v = ((const unsigned int*)row)[lane];
  lo = __uint_as_float(v << 16);
  hi = __uint_as_float(v & 0xffff0000u);
}

// ---------------- CSR build ----------------
__global__ void cnt_kernel(const int* __restrict__ ei, int* __restrict__ cnt, int E) {
  int e = blockIdx.x * 256 + threadIdx.x;
  if (e < E) atomicAdd(&cnt[ei[E + e]], 1);
}

// multi-block exclusive scan: bsum -> bscan -> scatter
#define SCAN_TPB 256
#define SCAN_EPT 16
#define SCAN_EPB (SCAN_TPB * SCAN_EPT)

__global__ __launch_bounds__(SCAN_TPB) void bsum_kernel(const int* __restrict__ cnt,
                                                        int* __restrict__ bsum, int n) {
  __shared__ int sm[SCAN_TPB];
  int lo = blockIdx.x * SCAN_EPB + threadIdx.x * SCAN_EPT;
  int s = 0;
#pragma unroll
  for (int i = 0; i < SCAN_EPT; ++i) { int idx = lo + i; if (idx < n) s += cnt[idx]; }
  sm[threadIdx.x] = s;
  __syncthreads();
  for (int off = SCAN_TPB / 2; off; off >>= 1) {
    if (threadIdx.x < off) sm[threadIdx.x] += sm[threadIdx.x + off];
    __syncthreads();
  }
  if (threadIdx.x == 0) bsum[blockIdx.x] = sm[0];
}

__global__ __launch_bounds__(1024) void bscan_kernel(int* __restrict__ bsum, int nb) {
  __shared__ int sm[1024];
  int t = threadIdx.x;
  int v = (t < nb) ? bsum[t] : 0;
  sm[t] = v;
  __syncthreads();
  for (int off = 1; off < 1024; off <<= 1) {
    int u = (t >= off) ? sm[t - off] : 0;
    __syncthreads();
    sm[t] += u;
    __syncthreads();
  }
  if (t < nb) bsum[t] = sm[t] - v;  // exclusive
}

__global__ __launch_bounds__(SCAN_TPB) void scatter_scan_kernel(
    const int* __restrict__ cnt, const int* __restrict__ bsum,
    int* __restrict__ row_ptr, int* __restrict__ cursor, int n, int total) {
  __shared__ int sm[SCAN_TPB];
  int t = threadIdx.x;
  int lo = blockIdx.x * SCAN_EPB + t * SCAN_EPT;
  int loc[SCAN_EPT];
  int s = 0;
#pragma unroll
  for (int i = 0; i < SCAN_EPT; ++i) {
    int idx = lo + i;
    int c = (idx < n) ? cnt[idx] : 0;
    loc[i] = s; s += c;
  }
  sm[t] = s;
  __syncthreads();
  for (int off = 1; off < SCAN_TPB; off <<= 1) {
    int u = (t >= off) ? sm[t - off] : 0;
    __syncthreads();
    sm[t] += u;
    __syncthreads();
  }
  int base = sm[t] - s + bsum[blockIdx.x];
#pragma unroll
  for (int i = 0; i < SCAN_EPT; ++i) {
    int idx = lo + i;
    if (idx < n) { int v = base + loc[i]; row_ptr[idx] = v; cursor[idx] = v; }
  }
  if (blockIdx.x == 0 && t == 0) row_ptr[n] = total;
}

__global__ void fill_kernel(const int* __restrict__ ei, int* __restrict__ cursor,
                            int* __restrict__ col_idx, int E) {
  int e = blockIdx.x * 256 + threadIdx.x;
  if (e < E) {
    int d = ei[E + e];
    int p = atomicAdd(&cursor[d], 1);
    col_idx[p] = ei[e];
  }
}

// ---------------- input projection: out[n][128] = X[n][D] @ W.T + b ----------------
template<int D, typename T>
__global__ __launch_bounds__(256) void proj_kernel(const float* __restrict__ X,
    const float* __restrict__ W, const float* __restrict__ bias,
    T* __restrict__ out, int n) {
  __shared__ float wT[D][129];
  int tid = threadIdx.x, lane = tid & 63, wv = tid >> 6;
  for (int idx = tid; idx < 128 * D; idx += 256) {
    int k = idx % D, j = idx / D;
    wT[k][j] = W[idx];  // coalesced read of W[j][k]
  }
  __syncthreads();
  float b0 = bias[lane], b1 = bias[lane + 64];
  for (int row = blockIdx.x * 4 + wv; row < n; row += gridDim.x * 4) {
    const float4* xr = (const float4*)(X + (size_t)row * D);
    float a0 = b0, a1 = b1;
#pragma unroll
    for (int k4 = 0; k4 < D / 4; ++k4) {
      float4 x = xr[k4];
      int k = k4 * 4;
      a0 += x.x * wT[k][lane]      + x.y * wT[k + 1][lane]
          + x.z * wT[k + 2][lane]  + x.w * wT[k + 3][lane];
      a1 += x.x * wT[k][lane + 64]     + x.y * wT[k + 1][lane + 64]
          + x.z * wT[k + 2][lane + 64] + x.w * wT[k + 3][lane + 64];
    }
    stv(&out[(size_t)row * 128 + lane], a0);
    stv(&out[(size_t)row * 128 + 64 + lane], a1);
  }
}

// ---------------- fused SAGE: gather-mean + GEMMs + bias + L2-norm [+accum] ----
// out[row][0:DOUT] = l2norm( mean_{nbrs}(xsrc) @ Wl.T + bl + xd[row] @ Wr.T )
template<int DOUT, bool ACCUM, typename T>
__global__ __launch_bounds__(256) void sage_fused_kernel(
    const int* __restrict__ row_ptr, const int* __restrict__ col_idx,
    const T* __restrict__ xsrc, const T* __restrict__ xd,
    const float* __restrict__ Wl, const float* __restrict__ bl,
    const float* __restrict__ Wr, T* __restrict__ out, int n) {
  constexpr int NCOL = DOUT / 64;
  __shared__ float am[32][128];   // mean-aggregated neighbors
  __shared__ float ax[32][128];   // dst features
  __shared__ float wl_t[16][DOUT + 1];
  __shared__ float wr_t[16][DOUT + 1];
  const int tid = threadIdx.x;
  const int lane = tid & 63;
  const int wv = tid >> 6;
  const int base = blockIdx.x * 32;

  // ---- gather phase: each wave handles rows wv, wv+4, ... (8 rows) ----
  // lane covers elements {2*lane, 2*lane+1}: one 4B load per neighbor row.
  for (int r = wv; r < 32; r += 4) {
    int row = base + r;
    float a0 = 0.f, a1 = 0.f, x0 = 0.f, x1 = 0.f;
    if (row < n) {
      int beg = row_ptr[row], end = row_ptr[row + 1];
      for (int p = beg; p < end; ++p) {
        float lo, hi;
        load2(xsrc + (size_t)col_idx[p] * 128, lane, lo, hi);
        a0 += lo; a1 += hi;
      }
      float rc = (end > beg) ? 1.f / (float)(end - beg) : 0.f;
      a0 *= rc; a1 *= rc;
      load2(xd + (size_t)row * 128, lane, x0, x1);
    }
    *(float2*)&am[r][2 * lane] = make_float2(a0, a1);
    *(float2*)&ax[r][2 * lane] = make_float2(x0, x1);
  }

  float acc[8][NCOL];
#pragma unroll
  for (int r = 0; r < 8; ++r)
#pragma unroll
    for (int c = 0; c < NCOL; ++c) acc[r][c] = bl[lane + c * 64];

  // ---- K-loop: 8 tiles of 16 ----
  for (int k0 = 0; k0 < 128; k0 += 16) {
    __syncthreads();  // gather/previous-tile reads done before restaging W
    for (int idx = tid; idx < 16 * DOUT; idx += 256) {
      int kk = idx & 15, j = idx >> 4;
      wl_t[kk][j] = Wl[j * 128 + k0 + kk];
      wr_t[kk][j] = Wr[j * 128 + k0 + kk];
    }
    __syncthreads();
#pragma unroll
    for (int r = 0; r < 8; ++r) {
      int rr = wv * 8 + r;
      const float4* amp = (const float4*)&am[rr][k0];
      const float4* axp = (const float4*)&ax[rr][k0];
#pragma unroll
      for (int q = 0; q < 4; ++q) {
        float4 m4 = amp[q], x4 = axp[q];
        float mv[4] = {m4.x, m4.y, m4.z, m4.w};
        float xv[4] = {x4.x, x4.y, x4.z, x4.w};
#pragma unroll
        for (int s = 0; s < 4; ++s) {
          int kk = q * 4 + s;
          acc[r][0] += mv[s] * wl_t[kk][lane] + xv[s] * wr_t[kk][lane];
          if (NCOL == 2)
            acc[r][1] += mv[s] * wl_t[kk][lane + 64] + xv[s] * wr_t[kk][lane + 64];
        }
      }
    }
  }

  // ---- epilogue: row L2-norm, store / accumulate ----
#pragma unroll
  for (int r = 0; r < 8; ++r) {
    int row = base + wv * 8 + r;
    float ss = acc[r][0] * acc[r][0];
    if (NCOL == 2) ss += acc[r][1] * acc[r][1];
#pragma unroll
    for (int off = 32; off; off >>= 1) ss += __shfl_xor(ss, off);
    float rn = 1.0f / fmaxf(sqrtf(ss), 1e-12f);
    if (row < n) {
      T* op = out + (size_t)row * DOUT;
      if (ACCUM) {
        stv(op + lane, ldv(op + lane) + acc[r][0] * rn);
        if (NCOL == 2) stv(op + 64 + lane, ldv(op + 64 + lane) + acc[r][1] * rn);
      } else {
        stv(op + lane, acc[r][0] * rn);
        if (NCOL == 2) stv(op + 64 + lane, acc[r][1] * rn);
      }
    }
  }
}

// ---------------- BatchNorm (training-mode batch stats) ----------------
template<int C, typename T>
__global__ __launch_bounds__(256) void bn_stats_kernel(const T* __restrict__ x,
    float* __restrict__ stats, int n) {
  constexpr int RPB = 256 / C;
  int c = threadIdx.x % C;
  float s = 0.f, ss = 0.f;
  for (int r = blockIdx.x * RPB + threadIdx.x / C; r < n; r += gridDim.x * RPB) {
    float v = ldv(x + (size_t)r * C + c);
    s += v; ss += v * v;
  }
  atomicAdd(&stats[c], s);
  atomicAdd(&stats[C + c], ss);
}

template<int C, bool RELU, typename T>
__global__ __launch_bounds__(256) void bn_apply_kernel(T* __restrict__ x,
    const float* __restrict__ stats, const float* __restrict__ g,
    const float* __restrict__ b, int n) {
  size_t i = (size_t)blockIdx.x * 256 + threadIdx.x;
  size_t total = (size_t)n * C;
  if (i >= total) return;
  int c = (int)(i & (C - 1));
  float rn = 1.f / (float)n;
  float mu = stats[c] * rn;
  float var = stats[C + c] * rn - mu * mu;
  float v = (ldv(&x[i]) - mu) * rsqrtf(var + EPS_BN) * g[c] + b[c];
  if (RELU) v = fmaxf(v, 0.f);
  stv(&x[i], v);
}

// ---------------- classifier: out[n] = relu(X @ W1.T + b1) @ W2.T + b2 ------
template<typename T>
__global__ __launch_bounds__(256) void clf_kernel(const T* __restrict__ X,
    const float* __restrict__ W1, const float* __restrict__ b1,
    const float* __restrict__ W2, const float* __restrict__ b2,
    float* __restrict__ out, int n) {
  __shared__ float w1T[64][65];
  __shared__ float w2s[64];
  int tid = threadIdx.x, lane = tid & 63, wv = tid >> 6;
  for (int idx = tid; idx < 4096; idx += 256) {
    int k = idx & 63, j = idx >> 6;
    w1T[k][j] = W1[idx];
  }
  if (tid < 64) w2s[tid] = W2[tid];
  __syncthreads();
  float bb = b1[lane];
  float b2v = b2[0];
  for (int row = blockIdx.x * 4 + wv; row < n; row += gridDim.x * 4) {
    const T* xr = X + (size_t)row * 64;
    float acc = bb;
#pragma unroll
    for (int k = 0; k < 64; ++k) acc += ldv(xr + k) * w1T[k][lane];
    float h = fmaxf(acc, 0.f) * w2s[lane];
#pragma unroll
    for (int off = 32; off; off >>= 1) h += __shfl_xor(h, off);
    if (lane == 0) out[row] = h + b2v;
  }
}

// ---------------- one hetero layer ----------------
template<int DO, bool RELU, typename T>
static void run_layer(const float* Wl, const float* bl, const float* Wr,
                      const float* g, const float* b,
                      const T* xa, const T* xm, T* oa, T* om, float* STATS,
                      const int* rp_p, const int* ci_p,
                      const int* rp_r, const int* ci_r,
                      const int* rp_t, const int* ci_t,
                      int NA, int NM, hipStream_t stream) {
  // pays: account -> merchant
  sage_fused_kernel<DO, false, T><<<idiv(NM, 32), 256, 0, stream>>>(
      rp_p, ci_p, xa, xm, Wl, bl, Wr, om, NM);
  // rev_pays: merchant -> account
  sage_fused_kernel<DO, false, T><<<idiv(NA, 32), 256, 0, stream>>>(
      rp_r, ci_r, xm, xa, Wl + DO * 128, bl + DO, Wr + DO * 128, oa, NA);
  // transfer: account -> account (accumulate)
  sage_fused_kernel<DO, true, T><<<idiv(NA, 32), 256, 0, stream>>>(
      rp_t, ci_t, xa, xa, Wl + 2 * DO * 128, bl + 2 * DO, Wr + 2 * DO * 128, oa, NA);
  // BN account
  hipMemsetAsync(STATS, 0, 2 * DO * sizeof(float), stream);
  bn_stats_kernel<DO, T><<<1024, 256, 0, stream>>>(oa, STATS, NA);
  bn_apply_kernel<DO, RELU, T><<<idiv(NA * DO, 256), 256, 0, stream>>>(oa, STATS, g, b, NA);
  // BN merchant
  hipMemsetAsync(STATS, 0, 2 * DO * sizeof(float), stream);
  bn_stats_kernel<DO, T><<<1024, 256, 0, stream>>>(om, STATS, NM);
  bn_apply_kernel<DO, RELU, T><<<idiv(NM * DO, 256), 256, 0, stream>>>(om, STATS, g + DO, b + DO, NM);
}

static size_t ws_need(int NA, int NM, int E, size_t esz) {
  size_t acts = ((size_t)2 * NA * 128 + (size_t)2 * NM * 128) * esz;
  acts = (acts + 15) & ~(size_t)15;
  size_t stats = 256 * 4;
  size_t ints = ((size_t)(NM + 1) + NM + E + 2 * ((size_t)(NA + 1) + NA + E) + NA + 1024) * 4;
  return acts + stats + ints + 64;
}

template<typename T>
static void run_all(void* const* d_in, float* d_out, void* d_ws,
                    int NA, int NM, int E, hipStream_t stream) {
  const float* x_acc = (const float*)d_in[0];
  const float* x_mer = (const float*)d_in[1];
  const int* ei_pays = (const int*)d_in[2];
  const int* ei_rev  = (const int*)d_in[3];
  const int* ei_tr   = (const int*)d_in[4];
  const float* pWa = (const float*)d_in[5];
  const float* pba = (const float*)d_in[6];
  const float* pWm = (const float*)d_in[7];
  const float* pbm = (const float*)d_in[8];
  const float* Wl[3]  = {(const float*)d_in[9],  (const float*)d_in[12], (const float*)d_in[15]};
  const float* blp[3] = {(const float*)d_in[10], (const float*)d_in[13], (const float*)d_in[16]};
  const float* Wr[3]  = {(const float*)d_in[11], (const float*)d_in[14], (const float*)d_in[17]};
  const float* bng[3] = {(const float*)d_in[18], (const float*)d_in[20], (const float*)d_in[22]};
  const float* bnb[3] = {(const float*)d_in[19], (const float*)d_in[21], (const float*)d_in[23]};
  const float* cW1 = (const float*)d_in[24];
  const float* cb1 = (const float*)d_in[25];
  const float* cW2 = (const float*)d_in[26];
  const float* cb2 = (const float*)d_in[27];

  char* p = (char*)d_ws;
  T* A0 = (T*)p; p += (size_t)NA * 128 * sizeof(T);
  T* A1 = (T*)p; p += (size_t)NA * 128 * sizeof(T);
  T* M0 = (T*)p; p += (size_t)NM * 128 * sizeof(T);
  T* M1 = (T*)p; p += (size_t)NM * 128 * sizeof(T);
  p = (char*)(((uintptr_t)p + 15) & ~(uintptr_t)15);
  float* STATS = (float*)p; p += 256 * 4;
  int* rp_p  = (int*)p; p += ((size_t)NM + 1) * 4;
  int* cur_p = (int*)p; p += (size_t)NM * 4;
  int* ci_p  = (int*)p; p += (size_t)E * 4;
  int* rp_r  = (int*)p; p += ((size_t)NA + 1) * 4;
  int* cur_r = (int*)p; p += (size_t)NA * 4;
  int* ci_r  = (int*)p; p += (size_t)E * 4;
  int* rp_t  = (int*)p; p += ((size_t)NA + 1) * 4;
  int* cur_t = (int*)p; p += (size_t)NA * 4;
  int* ci_t  = (int*)p; p += (size_t)E * 4;
  int* icnt  = (int*)p; p += (size_t)NA * 4;
  int* bsum  = (int*)p; p += 1024 * 4;

  // ---- CSR builds (edges identical across layers: build once) ----
  struct ET { const int* ei; int nd; int* rp; int* cur; int* ci; };
  ET et[3] = {
      {ei_pays, NM, rp_p, cur_p, ci_p},
      {ei_rev,  NA, rp_r, cur_r, ci_r},
      {ei_tr,   NA, rp_t, cur_t, ci_t},
  };
  for (int t = 0; t < 3; ++t) {
    hipMemsetAsync(icnt, 0, (size_t)et[t].nd * sizeof(int), stream);
    cnt_kernel<<<idiv(E, 256), 256, 0, stream>>>(et[t].ei, icnt, E);
    int nb = idiv(et[t].nd, SCAN_EPB);
    bsum_kernel<<<nb, SCAN_TPB, 0, stream>>>(icnt, bsum, et[t].nd);
    bscan_kernel<<<1, 1024, 0, stream>>>(bsum, nb);
    scatter_scan_kernel<<<nb, SCAN_TPB, 0, stream>>>(icnt, bsum, et[t].rp, et[t].cur,
                                                     et[t].nd, E);
    fill_kernel<<<idiv(E, 256), 256, 0, stream>>>(et[t].ei, et[t].cur, et[t].ci, E);
  }

  // ---- input projections ----
  proj_kernel<64, T><<<4096, 256, 0, stream>>>(x_acc, pWa, pba, A0, NA);
  proj_kernel<32, T><<<4096, 256, 0, stream>>>(x_mer, pWm, pbm, M0, NM);

  // ---- 3 hetero layers ----
  T *xa = A0, *xm = M0, *oa = A1, *om = M1;
  run_layer<128, true, T>(Wl[0], blp[0], Wr[0], bng[0], bnb[0], xa, xm, oa, om, STATS,
                          rp_p, ci_p, rp_r, ci_r, rp_t, ci_t, NA, NM, stream);
  { T* t = xa; xa = oa; oa = t; t = xm; xm = om; om = t; }
  run_layer<128, true, T>(Wl[1], blp[1], Wr[1], bng[1], bnb[1], xa, xm, oa, om, STATS,
                          rp_p, ci_p, rp_r, ci_r, rp_t, ci_t, NA, NM, stream);
  { T* t = xa; xa = oa; oa = t; t = xm; xm = om; om = t; }
  run_layer<64, false, T>(Wl[2], blp[2], Wr[2], bng[2], bnb[2], xa, xm, oa, om, STATS,
                          rp_p, ci_p, rp_r, ci_r, rp_t, ci_t, NA, NM, stream);
  { T* t = xa; xa = oa; oa = t; t = xm; xm = om; om = t; }

  // ---- classifier head on accounts ----
  clf_kernel<T><<<4096, 256, 0, stream>>>(xa, cW1, cb1, cW2, cb2, d_out, NA);
}

extern "C" void kernel_launch(void* const* d_in, const int* in_sizes, int n_in,
                              void* d_out, int out_size, void* d_ws, size_t ws_size,
                              hipStream_t stream) {
  const int NA = in_sizes[0] / 64;   // 200000
  const int NM = in_sizes[1] / 32;   // 100000
  const int E  = in_sizes[2] / 2;    // 500000

  if (ws_size >= ws_need(NA, NM, E, sizeof(float))) {
    run_all<float>(d_in, (float*)d_out, d_ws, NA, NM, E, stream);
  } else if (ws_size >= ws_need(NA, NM, E, sizeof(__hip_bfloat16))) {
    run_all<__hip_bfloat16>(d_in, (float*)d_out, d_ws, NA, NM, E, stream);
  }
  // else: insufficient scratch — leave output untouched (signals ws too small)
}

// Round 4
// 2269.590 us; speedup vs baseline: 2.3142x; 1.8090x over previous
//
#include <hip/hip_runtime.h>
#include <hip/hip_bf16.h>
#include <cstdint>
#include <cstddef>

#define EPS_BN 1e-5f

typedef unsigned short ushort_t;
typedef __attribute__((ext_vector_type(8))) short short8;
typedef __attribute__((ext_vector_type(4))) float f32x4;

static inline int idiv(int a, int b) { return (a + b - 1) / b; }

__device__ __forceinline__ float ldv(const __hip_bfloat16* p) { return __bfloat162float(*p); }
__device__ __forceinline__ void stv(__hip_bfloat16* p, float v) { *p = __float2bfloat16(v); }

__device__ __forceinline__ ushort_t f2bf(float x) {
  __hip_bfloat16 h = __float2bfloat16(x);
  return *reinterpret_cast<ushort_t*>(&h);
}
__device__ __forceinline__ float bf2f(ushort_t u) {
  unsigned v = (unsigned)u << 16;
  return __uint_as_float(v);
}

// ---------------- CSR build ----------------
__global__ void cnt_kernel(const int* __restrict__ ei, int* __restrict__ cnt, int E) {
  int e = blockIdx.x * 256 + threadIdx.x;
  if (e < E) atomicAdd(&cnt[ei[E + e]], 1);
}

#define SCAN_TPB 256
#define SCAN_EPT 16
#define SCAN_EPB (SCAN_TPB * SCAN_EPT)

__global__ __launch_bounds__(SCAN_TPB) void bsum_kernel(const int* __restrict__ cnt,
                                                        int* __restrict__ bsum, int n) {
  __shared__ int sm[SCAN_TPB];
  int lo = blockIdx.x * SCAN_EPB + threadIdx.x * SCAN_EPT;
  int s = 0;
#pragma unroll
  for (int i = 0; i < SCAN_EPT; ++i) { int idx = lo + i; if (idx < n) s += cnt[idx]; }
  sm[threadIdx.x] = s;
  __syncthreads();
  for (int off = SCAN_TPB / 2; off; off >>= 1) {
    if (threadIdx.x < off) sm[threadIdx.x] += sm[threadIdx.x + off];
    __syncthreads();
  }
  if (threadIdx.x == 0) bsum[blockIdx.x] = sm[0];
}

__global__ __launch_bounds__(1024) void bscan_kernel(int* __restrict__ bsum, int nb) {
  __shared__ int sm[1024];
  int t = threadIdx.x;
  int v = (t < nb) ? bsum[t] : 0;
  sm[t] = v;
  __syncthreads();
  for (int off = 1; off < 1024; off <<= 1) {
    int u = (t >= off) ? sm[t - off] : 0;
    __syncthreads();
    sm[t] += u;
    __syncthreads();
  }
  if (t < nb) bsum[t] = sm[t] - v;  // exclusive
}

// reads counts from cntcur, writes row_ptr and overwrites cntcur with cursor
__global__ __launch_bounds__(SCAN_TPB) void scatter_scan_kernel(
    int* cntcur, const int* __restrict__ bsum,
    int* __restrict__ row_ptr, int n, int total) {
  __shared__ int sm[SCAN_TPB];
  int t = threadIdx.x;
  int lo = blockIdx.x * SCAN_EPB + t * SCAN_EPT;
  int loc[SCAN_EPT];
  int s = 0;
#pragma unroll
  for (int i = 0; i < SCAN_EPT; ++i) {
    int idx = lo + i;
    int c = (idx < n) ? cntcur[idx] : 0;
    loc[i] = s; s += c;
  }
  sm[t] = s;
  __syncthreads();
  for (int off = 1; off < SCAN_TPB; off <<= 1) {
    int u = (t >= off) ? sm[t - off] : 0;
    __syncthreads();
    sm[t] += u;
    __syncthreads();
  }
  int base = sm[t] - s + bsum[blockIdx.x];
#pragma unroll
  for (int i = 0; i < SCAN_EPT; ++i) {
    int idx = lo + i;
    if (idx < n) { int v = base + loc[i]; row_ptr[idx] = v; cntcur[idx] = v; }
  }
  if (blockIdx.x == 0 && t == 0) row_ptr[n] = total;
}

__global__ void fill_kernel(const int* __restrict__ ei, int* __restrict__ cursor,
                            int* __restrict__ col_idx, int E) {
  int e = blockIdx.x * 256 + threadIdx.x;
  if (e < E) {
    int d = ei[E + e];
    int p = atomicAdd(&cursor[d], 1);
    col_idx[p] = ei[e];
  }
}

// ---------------- W prep: fp32 [3][DOUT][128] (Wl,Wr) -> bf16 hi/lo k-tiled ----
// dst per edge-type: [mat(2)][hilo(2)][kt(4)][DOUT][32], et-stride = 16*DOUT*32
__global__ void wprep_kernel(const float* __restrict__ Wl, const float* __restrict__ Wr,
                             ushort_t* __restrict__ dst, int DOUT) {
  int idx = blockIdx.x * 256 + threadIdx.x;
  int per_mat = DOUT * 128;
  int total = 3 * 2 * per_mat;
  if (idx >= total) return;
  int et = idx / (2 * per_mat);
  int r = idx % (2 * per_mat);
  int mat = r / per_mat;
  int e = r % per_mat;
  int nrow = e / 128, k = e % 128;
  const float* src = mat ? Wr : Wl;
  float w = src[et * per_mat + nrow * 128 + k];
  ushort_t hi = f2bf(w);
  ushort_t lo = f2bf(w - bf2f(hi));
  int kt = k >> 5, kk = k & 31;
  int pos = kt * DOUT * 32 + nrow * 32 + kk;
  size_t etbase = (size_t)et * (16 * DOUT * 32);
  int MB = 4 * DOUT * 32;
  dst[etbase + (size_t)(mat * 2 + 0) * MB + pos] = hi;
  dst[etbase + (size_t)(mat * 2 + 1) * MB + pos] = lo;
}

// ---------------- input projection: out[n][128] = X[n][D] @ W.T + b (bf16 out) ----
template<int D>
__global__ __launch_bounds__(256) void proj_kernel(const float* __restrict__ X,
    const float* __restrict__ W, const float* __restrict__ bias,
    __hip_bfloat16* __restrict__ out, int n) {
  __shared__ float wT[D][129];
  int tid = threadIdx.x, lane = tid & 63, wv = tid >> 6;
  for (int idx = tid; idx < 128 * D; idx += 256) {
    int k = idx % D, j = idx / D;
    wT[k][j] = W[idx];
  }
  __syncthreads();
  float b0 = bias[lane], b1 = bias[lane + 64];
  for (int row = blockIdx.x * 4 + wv; row < n; row += gridDim.x * 4) {
    const float4* xr = (const float4*)(X + (size_t)row * D);
    float a0 = b0, a1 = b1;
#pragma unroll
    for (int k4 = 0; k4 < D / 4; ++k4) {
      float4 x = xr[k4];
      int k = k4 * 4;
      a0 += x.x * wT[k][lane]      + x.y * wT[k + 1][lane]
          + x.z * wT[k + 2][lane]  + x.w * wT[k + 3][lane];
      a1 += x.x * wT[k][lane + 64]     + x.y * wT[k + 1][lane + 64]
          + x.z * wT[k + 2][lane + 64] + x.w * wT[k + 3][lane + 64];
    }
    stv(&out[(size_t)row * 128 + lane], a0);
    stv(&out[(size_t)row * 128 + 64 + lane], a1);
  }
}

// ---------------- fused SAGE via MFMA ----------------
// out[row][:] = l2norm( mean_nbr(xsrc) @ Wl.T + bl + xd[row] @ Wr.T )  [+= if ACCUM]
// A-frags (mean, xd) from XOR-swizzled LDS; B-frags (W hi/lo) direct from global.
template<int DOUT, bool ACCUM>
__global__ __launch_bounds__(256, 4) void sage_mfma_kernel(
    const int* __restrict__ row_ptr, const int* __restrict__ col_idx,
    const ushort_t* __restrict__ xsrc, const ushort_t* __restrict__ xd,
    const ushort_t* __restrict__ Wb, const float* __restrict__ bl,
    ushort_t* __restrict__ out, int n) {
  constexpr int NCT = DOUT / 32;        // col-tiles of 16 per wave (wave = DOUT/2 cols)
  constexpr int MB = 4 * DOUT * 32;     // per (mat,hilo) block in Wb
  __shared__ __align__(16) ushort_t am[32][128];
  __shared__ __align__(16) ushort_t ax[32][128];
  __shared__ float ssb[32][2];
  const int tid = threadIdx.x, lane = tid & 63, wv = tid >> 6;
  const int base = blockIdx.x * 32;

  // ---- gather-mean into swizzled bf16 LDS tiles ----
  for (int r = wv; r < 32; r += 4) {
    int row = base + r;
    unsigned mv = 0, xv = 0;
    if (row < n) {
      int beg = row_ptr[row], end = row_ptr[row + 1];
      float a0 = 0.f, a1 = 0.f;
      for (int p = beg; p < end; ++p) {
        unsigned v = ((const unsigned*)(xsrc + (size_t)col_idx[p] * 128))[lane];
        a0 += __uint_as_float(v << 16);
        a1 += __uint_as_float(v & 0xffff0000u);
      }
      float rc = (end > beg) ? 1.f / (float)(end - beg) : 0.f;
      mv = (unsigned)f2bf(a0 * rc) | ((unsigned)f2bf(a1 * rc) << 16);
      xv = ((const unsigned*)(xd + (size_t)row * 128))[lane];
    }
    int bo = (lane * 4) ^ ((r & 7) << 4);
    *(unsigned*)((char*)&am[r][0] + bo) = mv;
    *(unsigned*)((char*)&ax[r][0] + bo) = xv;
  }
  __syncthreads();

  const int rt = wv >> 1;               // row-tile 0..1 (16 rows each)
  const int half = wv & 1;              // col half
  const int colbase = half * (DOUT / 2);
  const int cn = lane & 15;
  const int g = lane >> 4;              // k-octet group

  f32x4 acc[NCT];
#pragma unroll
  for (int ct = 0; ct < NCT; ++ct) {
    float b = bl[colbase + ct * 16 + cn];
    acc[ct] = (f32x4){b, b, b, b};
  }

  const int arow = rt * 16 + cn;        // A row this lane feeds
  const char* amrow = (const char*)&am[arow][0];
  const char* axrow = (const char*)&ax[arow][0];
  const int axor = (arow & 7) << 4;

#pragma unroll
  for (int kt = 0; kt < 4; ++kt) {
    int aoff = (kt * 64 + g * 16) ^ axor;
    short8 a_m = *(const short8*)(amrow + aoff);
    short8 a_x = *(const short8*)(axrow + aoff);
    int nbase = kt * DOUT * 32 + (colbase + cn) * 32 + 8 * g;
#pragma unroll
    for (int ct = 0; ct < NCT; ++ct) {
      int no = nbase + ct * 16 * 32;
      short8 wlh = *(const short8*)(Wb + 0 * MB + no);
      short8 wll = *(const short8*)(Wb + 1 * MB + no);
      short8 wrh = *(const short8*)(Wb + 2 * MB + no);
      short8 wrl = *(const short8*)(Wb + 3 * MB + no);
      acc[ct] = __builtin_amdgcn_mfma_f32_16x16x32_bf16(a_m, wlh, acc[ct], 0, 0, 0);
      acc[ct] = __builtin_amdgcn_mfma_f32_16x16x32_bf16(a_m, wll, acc[ct], 0, 0, 0);
      acc[ct] = __builtin_amdgcn_mfma_f32_16x16x32_bf16(a_x, wrh, acc[ct], 0, 0, 0);
      acc[ct] = __builtin_amdgcn_mfma_f32_16x16x32_bf16(a_x, wrl, acc[ct], 0, 0, 0);
    }
  }

  // ---- row L2-norm: reduce 16 col-lanes, combine wave halves via LDS ----
  float p[4];
#pragma unroll
  for (int i = 0; i < 4; ++i) {
    float s = 0.f;
#pragma unroll
    for (int ct = 0; ct < NCT; ++ct) s += acc[ct][i] * acc[ct][i];
#pragma unroll
    for (int m = 1; m < 16; m <<= 1) s += __shfl_xor(s, m);
    p[i] = s;
  }
  if (cn == 0) {
#pragma unroll
    for (int i = 0; i < 4; ++i) ssb[rt * 16 + g * 4 + i][half] = p[i];
  }
  __syncthreads();

#pragma unroll
  for (int i = 0; i < 4; ++i) {
    int rloc = rt * 16 + g * 4 + i;     // D-row this lane holds (reg i)
    int row = base + rloc;
    float ss = ssb[rloc][0] + ssb[rloc][1];
    float rn = 1.0f / fmaxf(sqrtf(ss), 1e-12f);
    if (row < n) {
      ushort_t* op = out + (size_t)row * DOUT + colbase + cn;
#pragma unroll
      for (int ct = 0; ct < NCT; ++ct) {
        float v = acc[ct][i] * rn;
        if (ACCUM) v += bf2f(op[ct * 16]);
        op[ct * 16] = f2bf(v);
      }
    }
  }
}

// ---------------- BatchNorm (training-mode batch stats) ----------------
template<int C>
__global__ __launch_bounds__(256) void bn_stats_kernel(const __hip_bfloat16* __restrict__ x,
    float* __restrict__ stats, int n) {
  constexpr int RPB = 256 / C;
  int c = threadIdx.x % C;
  float s = 0.f, ss = 0.f;
  for (int r = blockIdx.x * RPB + threadIdx.x / C; r < n; r += gridDim.x * RPB) {
    float v = ldv(x + (size_t)r * C + c);
    s += v; ss += v * v;
  }
  atomicAdd(&stats[c], s);
  atomicAdd(&stats[C + c], ss);
}

template<int C, bool RELU>
__global__ __launch_bounds__(256) void bn_apply_kernel(__hip_bfloat16* __restrict__ x,
    const float* __restrict__ stats, const float* __restrict__ g,
    const float* __restrict__ b, int n) {
  size_t i = (size_t)blockIdx.x * 256 + threadIdx.x;
  size_t total = (size_t)n * C;
  if (i >= total) return;
  int c = (int)(i & (C - 1));
  float rn = 1.f / (float)n;
  float mu = stats[c] * rn;
  float var = stats[C + c] * rn - mu * mu;
  float v = (ldv(&x[i]) - mu) * rsqrtf(var + EPS_BN) * g[c] + b[c];
  if (RELU) v = fmaxf(v, 0.f);
  stv(&x[i], v);
}

// ---------------- classifier: out[n] = relu(X @ W1.T + b1) @ W2.T + b2 ------
__global__ __launch_bounds__(256) void clf_kernel(const __hip_bfloat16* __restrict__ X,
    const float* __restrict__ W1, const float* __restrict__ b1,
    const float* __restrict__ W2, const float* __restrict__ b2,
    float* __restrict__ out, int n) {
  __shared__ float w1T[64][65];
  __shared__ float w2s[64];
  int tid = threadIdx.x, lane = tid & 63, wv = tid >> 6;
  for (int idx = tid; idx < 4096; idx += 256) {
    int k = idx & 63, j = idx >> 6;
    w1T[k][j] = W1[idx];
  }
  if (tid < 64) w2s[tid] = W2[tid];
  __syncthreads();
  float bb = b1[lane];
  float b2v = b2[0];
  for (int row = blockIdx.x * 4 + wv; row < n; row += gridDim.x * 4) {
    const __hip_bfloat16* xr = X + (size_t)row * 64;
    float acc = bb;
#pragma unroll
    for (int k = 0; k < 64; ++k) acc += ldv(xr + k) * w1T[k][lane];
    float h = fmaxf(acc, 0.f) * w2s[lane];
#pragma unroll
    for (int off = 32; off; off >>= 1) h += __shfl_xor(h, off);
    if (lane == 0) out[row] = h + b2v;
  }
}

// ---------------- one hetero layer ----------------
template<int DO, bool RELU>
static void run_layer(const ushort_t* WB, const float* bl,
                      const float* g, const float* b,
                      const ushort_t* xa, const ushort_t* xm,
                      ushort_t* oa, ushort_t* om, float* STATS,
                      const int* rp_p, const int* ci_p,
                      const int* rp_r, const int* ci_r,
                      const int* rp_t, const int* ci_t,
                      int NA, int NM, hipStream_t stream) {
  const size_t ETS = (size_t)16 * DO * 32;  // et-stride in Wb
  // pays: account -> merchant
  sage_mfma_kernel<DO, false><<<idiv(NM, 32), 256, 0, stream>>>(
      rp_p, ci_p, xa, xm, WB + 0 * ETS, bl, om, NM);
  // rev_pays: merchant -> account
  sage_mfma_kernel<DO, false><<<idiv(NA, 32), 256, 0, stream>>>(
      rp_r, ci_r, xm, xa, WB + 1 * ETS, bl + DO, oa, NA);
  // transfer: account -> account (accumulate)
  sage_mfma_kernel<DO, true><<<idiv(NA, 32), 256, 0, stream>>>(
      rp_t, ci_t, xa, xa, WB + 2 * ETS, bl + 2 * DO, oa, NA);
  // BN account
  hipMemsetAsync(STATS, 0, 2 * DO * sizeof(float), stream);
  bn_stats_kernel<DO><<<1024, 256, 0, stream>>>((const __hip_bfloat16*)oa, STATS, NA);
  bn_apply_kernel<DO, RELU><<<idiv(NA * DO, 256), 256, 0, stream>>>(
      (__hip_bfloat16*)oa, STATS, g, b, NA);
  // BN merchant
  hipMemsetAsync(STATS, 0, 2 * DO * sizeof(float), stream);
  bn_stats_kernel<DO><<<1024, 256, 0, stream>>>((const __hip_bfloat16*)om, STATS, NM);
  bn_apply_kernel<DO, RELU><<<idiv(NM * DO, 256), 256, 0, stream>>>(
      (__hip_bfloat16*)om, STATS, g + DO, b + DO, NM);
}

static size_t ws_need(int NA, int NM, int E) {
  size_t acts = ((size_t)2 * NA * 128 + (size_t)2 * NM * 128) * 2;
  size_t wbuf = ((size_t)2 * 196608 + 98304) * 2;   // L0+L1+L2 bf16 hi/lo
  size_t stats = 256 * 4;
  size_t ints = ((size_t)(NM + 1) + NM + E
               + 2 * ((size_t)(NA + 1) + NA + E) + 1024) * 4;
  return acts + wbuf + stats + ints + 256;
}

extern "C" void kernel_launch(void* const* d_in, const int* in_sizes, int n_in,
                              void* d_out, int out_size, void* d_ws, size_t ws_size,
                              hipStream_t stream) {
  const int NA = in_sizes[0] / 64;   // 200000
  const int NM = in_sizes[1] / 32;   // 100000
  const int E  = in_sizes[2] / 2;    // 500000
  if (ws_size < ws_need(NA, NM, E)) return;

  const float* x_acc = (const float*)d_in[0];
  const float* x_mer = (const float*)d_in[1];
  const int* ei_pays = (const int*)d_in[2];
  const int* ei_rev  = (const int*)d_in[3];
  const int* ei_tr   = (const int*)d_in[4];
  const float* pWa = (const float*)d_in[5];
  const float* pba = (const float*)d_in[6];
  const float* pWm = (const float*)d_in[7];
  const float* pbm = (const float*)d_in[8];
  const float* Wl[3]  = {(const float*)d_in[9],  (const float*)d_in[12], (const float*)d_in[15]};
  const float* blp[3] = {(const float*)d_in[10], (const float*)d_in[13], (const float*)d_in[16]};
  const float* Wr[3]  = {(const float*)d_in[11], (const float*)d_in[14], (const float*)d_in[17]};
  const float* bng[3] = {(const float*)d_in[18], (const float*)d_in[20], (const float*)d_in[22]};
  const float* bnb[3] = {(const float*)d_in[19], (const float*)d_in[21], (const float*)d_in[23]};
  const float* cW1 = (const float*)d_in[24];
  const float* cb1 = (const float*)d_in[25];
  const float* cW2 = (const float*)d_in[26];
  const float* cb2 = (const float*)d_in[27];

  char* p = (char*)d_ws;
  ushort_t* A0 = (ushort_t*)p; p += (size_t)NA * 128 * 2;
  ushort_t* A1 = (ushort_t*)p; p += (size_t)NA * 128 * 2;
  ushort_t* M0 = (ushort_t*)p; p += (size_t)NM * 128 * 2;
  ushort_t* M1 = (ushort_t*)p; p += (size_t)NM * 128 * 2;
  ushort_t* WB0 = (ushort_t*)p; p += (size_t)196608 * 2;
  ushort_t* WB1 = (ushort_t*)p; p += (size_t)196608 * 2;
  ushort_t* WB2 = (ushort_t*)p; p += (size_t)98304 * 2;
  p = (char*)(((uintptr_t)p + 15) & ~(uintptr_t)15);
  float* STATS = (float*)p; p += 256 * 4;
  int* rp_p  = (int*)p; p += ((size_t)NM + 1) * 4;
  int* cur_p = (int*)p; p += (size_t)NM * 4;
  int* ci_p  = (int*)p; p += (size_t)E * 4;
  int* rp_r  = (int*)p; p += ((size_t)NA + 1) * 4;
  int* cur_r = (int*)p; p += (size_t)NA * 4;
  int* ci_r  = (int*)p; p += (size_t)E * 4;
  int* rp_t  = (int*)p; p += ((size_t)NA + 1) * 4;
  int* cur_t = (int*)p; p += (size_t)NA * 4;
  int* ci_t  = (int*)p; p += (size_t)E * 4;
  int* bsum  = (int*)p; p += 1024 * 4;

  // ---- CSR builds (cur doubles as count buffer, then cursor) ----
  struct ET { const int* ei; int nd; int* rp; int* cur; int* ci; };
  ET et[3] = {
      {ei_pays, NM, rp_p, cur_p, ci_p},
      {ei_rev,  NA, rp_r, cur_r, ci_r},
      {ei_tr,   NA, rp_t, cur_t, ci_t},
  };
  for (int t = 0; t < 3; ++t) {
    hipMemsetAsync(et[t].cur, 0, (size_t)et[t].nd * sizeof(int), stream);
    cnt_kernel<<<idiv(E, 256), 256, 0, stream>>>(et[t].ei, et[t].cur, E);
    int nb = idiv(et[t].nd, SCAN_EPB);
    bsum_kernel<<<nb, SCAN_TPB, 0, stream>>>(et[t].cur, bsum, et[t].nd);
    bscan_kernel<<<1, 1024, 0, stream>>>(bsum, nb);
    scatter_scan_kernel<<<nb, SCAN_TPB, 0, stream>>>(et[t].cur, bsum, et[t].rp,
                                                     et[t].nd, E);
    fill_kernel<<<idiv(E, 256), 256, 0, stream>>>(et[t].ei, et[t].cur, et[t].ci, E);
  }

  // ---- W conversion to bf16 hi/lo, k-tiled ----
  wprep_kernel<<<idiv(3 * 2 * 128 * 128, 256), 256, 0, stream>>>(Wl[0], Wr[0], WB0, 128);
  wprep_kernel<<<idiv(3 * 2 * 128 * 128, 256), 256, 0, stream>>>(Wl[1], Wr[1], WB1, 128);
  wprep_kernel<<<idiv(3 * 2 * 64 * 128, 256), 256, 0, stream>>>(Wl[2], Wr[2], WB2, 64);

  // ---- input projections ----
  proj_kernel<64><<<4096, 256, 0, stream>>>(x_acc, pWa, pba, (__hip_bfloat16*)A0, NA);
  proj_kernel<32><<<4096, 256, 0, stream>>>(x_mer, pWm, pbm, (__hip_bfloat16*)M0, NM);

  // ---- 3 hetero layers ----
  ushort_t *xa = A0, *xm = M0, *oa = A1, *om = M1;
  run_layer<128, true>(WB0, blp[0], bng[0], bnb[0], xa, xm, oa, om, STATS,
                       rp_p, ci_p, rp_r, ci_r, rp_t, ci_t, NA, NM, stream);
  { ushort_t* t = xa; xa = oa; oa = t; t = xm; xm = om; om = t; }
  run_layer<128, true>(WB1, blp[1], bng[1], bnb[1], xa, xm, oa, om, STATS,
                       rp_p, ci_p, rp_r, ci_r, rp_t, ci_t, NA, NM, stream);
  { ushort_t* t = xa; xa = oa; oa = t; t = xm; xm = om; om = t; }
  run_layer<64, false>(WB2, blp[2], bng[2], bnb[2], xa, xm, oa, om, STATS,
                       rp_p, ci_p, rp_r, ci_r, rp_t, ci_t, NA, NM, stream);
  { ushort_t* t = xa; xa = oa; oa = t; t = xm; xm = om; om = t; }

  // ---- classifier head on accounts ----
  clf_kernel<<<4096, 256, 0, stream>>>((const __hip_bfloat16*)xa, cW1, cb1, cW2, cb2,
                                       (float*)d_out, NA);
}

// Round 5
// 2095.057 us; speedup vs baseline: 2.5070x; 1.0833x over previous
//
#include <hip/hip_runtime.h>
#include <hip/hip_bf16.h>
#include <cstdint>
#include <cstddef>

#define EPS_BN 1e-5f

typedef unsigned short ushort_t;
typedef __attribute__((ext_vector_type(8))) short short8;
typedef __attribute__((ext_vector_type(4))) float f32x4;

static inline int idiv(int a, int b) { return (a + b - 1) / b; }

__device__ __forceinline__ float ldv(const __hip_bfloat16* p) { return __bfloat162float(*p); }
__device__ __forceinline__ void stv(__hip_bfloat16* p, float v) { *p = __float2bfloat16(v); }

__device__ __forceinline__ ushort_t f2bf(float x) {
  __hip_bfloat16 h = __float2bfloat16(x);
  return *reinterpret_cast<ushort_t*>(&h);
}
__device__ __forceinline__ float bf2f(ushort_t u) {
  unsigned v = (unsigned)u << 16;
  return __uint_as_float(v);
}

// ---------------- CSR build ----------------
__global__ void cnt_kernel(const int* __restrict__ ei, int* __restrict__ cnt, int E) {
  int e = blockIdx.x * 256 + threadIdx.x;
  if (e < E) atomicAdd(&cnt[ei[E + e]], 1);
}

#define SCAN_TPB 256
#define SCAN_EPT 16
#define SCAN_EPB (SCAN_TPB * SCAN_EPT)

__global__ __launch_bounds__(SCAN_TPB) void bsum_kernel(const int* __restrict__ cnt,
                                                        int* __restrict__ bsum, int n) {
  __shared__ int sm[SCAN_TPB];
  int lo = blockIdx.x * SCAN_EPB + threadIdx.x * SCAN_EPT;
  int s = 0;
#pragma unroll
  for (int i = 0; i < SCAN_EPT; ++i) { int idx = lo + i; if (idx < n) s += cnt[idx]; }
  sm[threadIdx.x] = s;
  __syncthreads();
  for (int off = SCAN_TPB / 2; off; off >>= 1) {
    if (threadIdx.x < off) sm[threadIdx.x] += sm[threadIdx.x + off];
    __syncthreads();
  }
  if (threadIdx.x == 0) bsum[blockIdx.x] = sm[0];
}

__global__ __launch_bounds__(1024) void bscan_kernel(int* __restrict__ bsum, int nb) {
  __shared__ int sm[1024];
  int t = threadIdx.x;
  int v = (t < nb) ? bsum[t] : 0;
  sm[t] = v;
  __syncthreads();
  for (int off = 1; off < 1024; off <<= 1) {
    int u = (t >= off) ? sm[t - off] : 0;
    __syncthreads();
    sm[t] += u;
    __syncthreads();
  }
  if (t < nb) bsum[t] = sm[t] - v;  // exclusive
}

__global__ __launch_bounds__(SCAN_TPB) void scatter_scan_kernel(
    int* cntcur, const int* __restrict__ bsum,
    int* __restrict__ row_ptr, int n, int total) {
  __shared__ int sm[SCAN_TPB];
  int t = threadIdx.x;
  int lo = blockIdx.x * SCAN_EPB + t * SCAN_EPT;
  int loc[SCAN_EPT];
  int s = 0;
#pragma unroll
  for (int i = 0; i < SCAN_EPT; ++i) {
    int idx = lo + i;
    int c = (idx < n) ? cntcur[idx] : 0;
    loc[i] = s; s += c;
  }
  sm[t] = s;
  __syncthreads();
  for (int off = 1; off < SCAN_TPB; off <<= 1) {
    int u = (t >= off) ? sm[t - off] : 0;
    __syncthreads();
    sm[t] += u;
    __syncthreads();
  }
  int base = sm[t] - s + bsum[blockIdx.x];
#pragma unroll
  for (int i = 0; i < SCAN_EPT; ++i) {
    int idx = lo + i;
    if (idx < n) { int v = base + loc[i]; row_ptr[idx] = v; cntcur[idx] = v; }
  }
  if (blockIdx.x == 0 && t == 0) row_ptr[n] = total;
}

__global__ void fill_kernel(const int* __restrict__ ei, int* __restrict__ cursor,
                            int* __restrict__ col_idx, int E) {
  int e = blockIdx.x * 256 + threadIdx.x;
  if (e < E) {
    int d = ei[E + e];
    int p = atomicAdd(&cursor[d], 1);
    col_idx[p] = ei[e];
  }
}

// ---------------- W prep (sage): fp32 [3][DOUT][128] (Wl,Wr) -> bf16 hi/lo k-tiled
// dst per edge-type: [mat(2)][hilo(2)][kt(4)][DOUT][32], et-stride = 16*DOUT*32
__global__ void wprep_kernel(const float* __restrict__ Wl, const float* __restrict__ Wr,
                             ushort_t* __restrict__ dst, int DOUT) {
  int idx = blockIdx.x * 256 + threadIdx.x;
  int per_mat = DOUT * 128;
  int total = 3 * 2 * per_mat;
  if (idx >= total) return;
  int et = idx / (2 * per_mat);
  int r = idx % (2 * per_mat);
  int mat = r / per_mat;
  int e = r % per_mat;
  int nrow = e / 128, k = e % 128;
  const float* src = mat ? Wr : Wl;
  float w = src[et * per_mat + nrow * 128 + k];
  ushort_t hi = f2bf(w);
  ushort_t lo = f2bf(w - bf2f(hi));
  int kt = k >> 5, kk = k & 31;
  int pos = kt * DOUT * 32 + nrow * 32 + kk;
  size_t etbase = (size_t)et * (16 * DOUT * 32);
  int MB = 4 * DOUT * 32;
  dst[etbase + (size_t)(mat * 2 + 0) * MB + pos] = hi;
  dst[etbase + (size_t)(mat * 2 + 1) * MB + pos] = lo;
}

// ---------------- W prep (single matrix [DOUT][K]) -> [hilo(2)][kt][DOUT][32] ----
__global__ void wprep_one_kernel(const float* __restrict__ W, ushort_t* __restrict__ dst,
                                 int DOUT, int K) {
  int idx = blockIdx.x * 256 + threadIdx.x;
  if (idx >= DOUT * K) return;
  int row = idx / K, k = idx % K;
  float w = W[idx];
  ushort_t hi = f2bf(w);
  ushort_t lo = f2bf(w - bf2f(hi));
  int kt = k >> 5, kk = k & 31;
  int HB = (K >> 5) * DOUT * 32;
  int pos = kt * DOUT * 32 + row * 32 + kk;
  dst[pos] = hi;
  dst[HB + pos] = lo;
}

// ---------------- input projection via MFMA: out[n][128] = X[n][K] @ W.T + b ----
// x split hi/lo so effective input precision ~fp32 (xh@wh + xh@wl + xl@wh).
template<int K>
__global__ __launch_bounds__(256, 4) void proj_mfma_kernel(
    const float* __restrict__ X, const ushort_t* __restrict__ WP,
    const float* __restrict__ bias, ushort_t* __restrict__ out, int n) {
  constexpr int KT = K / 32;
  constexpr int HB = KT * 128 * 32;
  __shared__ __align__(16) ushort_t ah[32][2 * K];  // [hi | lo] per row
  const int tid = threadIdx.x, lane = tid & 63, wv = tid >> 6;
  const int base = blockIdx.x * 32;

  if (K == 64) {
    for (int r = wv; r < 32; r += 4) {
      int row = base + r;
      float v = (row < n) ? X[(size_t)row * 64 + lane] : 0.f;
      ushort_t hi = f2bf(v);
      ushort_t lo = f2bf(v - bf2f(hi));
      char* rp = (char*)&ah[r][0];
      int swz = (r & 7) << 4;
      *(ushort_t*)(rp + ((2 * lane) ^ swz)) = hi;
      *(ushort_t*)(rp + ((2 * K + 2 * lane) ^ swz)) = lo;
    }
  } else {
    for (int r = wv; r < 16; r += 4) {
      int rr = 2 * r + (lane >> 5);
      int row = base + rr;
      int el = lane & 31;
      float v = (row < n) ? X[(size_t)row * K + el] : 0.f;
      ushort_t hi = f2bf(v);
      ushort_t lo = f2bf(v - bf2f(hi));
      char* rp = (char*)&ah[rr][0];
      int swz = (rr & 7) << 4;
      *(ushort_t*)(rp + ((2 * el) ^ swz)) = hi;
      *(ushort_t*)(rp + ((2 * K + 2 * el) ^ swz)) = lo;
    }
  }
  __syncthreads();

  const int rt = wv >> 1, half = wv & 1;
  const int colbase = half * 64;
  const int cn = lane & 15, g = lane >> 4;

  f32x4 acc[4];
#pragma unroll
  for (int ct = 0; ct < 4; ++ct) {
    float b = bias[colbase + ct * 16 + cn];
    acc[ct] = (f32x4){b, b, b, b};
  }

  const int arow = rt * 16 + cn;
  const char* rowp = (const char*)&ah[arow][0];
  const int swz = (arow & 7) << 4;

#pragma unroll
  for (int kt = 0; kt < KT; ++kt) {
    int hb = kt * 64 + g * 16;
    short8 a_h = *(const short8*)(rowp + (hb ^ swz));
    short8 a_l = *(const short8*)(rowp + ((2 * K + hb) ^ swz));
#pragma unroll
    for (int ct = 0; ct < 4; ++ct) {
      int wb = kt * 128 * 32 + (colbase + ct * 16 + cn) * 32 + 8 * g;
      short8 wh = *(const short8*)(WP + wb);
      short8 wl = *(const short8*)(WP + HB + wb);
      acc[ct] = __builtin_amdgcn_mfma_f32_16x16x32_bf16(a_h, wh, acc[ct], 0, 0, 0);
      acc[ct] = __builtin_amdgcn_mfma_f32_16x16x32_bf16(a_h, wl, acc[ct], 0, 0, 0);
      acc[ct] = __builtin_amdgcn_mfma_f32_16x16x32_bf16(a_l, wh, acc[ct], 0, 0, 0);
    }
  }

#pragma unroll
  for (int i = 0; i < 4; ++i) {
    int rloc = rt * 16 + g * 4 + i;
    int row = base + rloc;
    if (row < n) {
      ushort_t* op = out + (size_t)row * 128 + colbase + cn;
#pragma unroll
      for (int ct = 0; ct < 4; ++ct) op[ct * 16] = f2bf(acc[ct][i]);
    }
  }
}

// ---------------- fused SAGE via MFMA (single edge type, plain store) ----------
template<int DOUT>
__global__ __launch_bounds__(256, 4) void sage_mfma_kernel(
    const int* __restrict__ row_ptr, const int* __restrict__ col_idx,
    const ushort_t* __restrict__ xsrc, const ushort_t* __restrict__ xd,
    const ushort_t* __restrict__ Wb, const float* __restrict__ bl,
    ushort_t* __restrict__ out, int n) {
  constexpr int NCT = DOUT / 32;
  constexpr int MB = 4 * DOUT * 32;
  __shared__ __align__(16) ushort_t am[32][128];
  __shared__ __align__(16) ushort_t ax[32][128];
  __shared__ float ssb[32][2];
  const int tid = threadIdx.x, lane = tid & 63, wv = tid >> 6;
  const int base = blockIdx.x * 32;

  for (int r = wv; r < 32; r += 4) {
    int row = base + r;
    unsigned mv = 0, xv = 0;
    if (row < n) {
      int beg = row_ptr[row], end = row_ptr[row + 1];
      float a0 = 0.f, a1 = 0.f;
      for (int p = beg; p < end; ++p) {
        unsigned v = ((const unsigned*)(xsrc + (size_t)col_idx[p] * 128))[lane];
        a0 += __uint_as_float(v << 16);
        a1 += __uint_as_float(v & 0xffff0000u);
      }
      float rc = (end > beg) ? 1.f / (float)(end - beg) : 0.f;
      mv = (unsigned)f2bf(a0 * rc) | ((unsigned)f2bf(a1 * rc) << 16);
      xv = ((const unsigned*)(xd + (size_t)row * 128))[lane];
    }
    int bo = (lane * 4) ^ ((r & 7) << 4);
    *(unsigned*)((char*)&am[r][0] + bo) = mv;
    *(unsigned*)((char*)&ax[r][0] + bo) = xv;
  }
  __syncthreads();

  const int rt = wv >> 1, half = wv & 1;
  const int colbase = half * (DOUT / 2);
  const int cn = lane & 15, g = lane >> 4;

  f32x4 acc[NCT];
#pragma unroll
  for (int ct = 0; ct < NCT; ++ct) {
    float b = bl[colbase + ct * 16 + cn];
    acc[ct] = (f32x4){b, b, b, b};
  }

  const int arow = rt * 16 + cn;
  const char* amrow = (const char*)&am[arow][0];
  const char* axrow = (const char*)&ax[arow][0];
  const int axor = (arow & 7) << 4;

#pragma unroll
  for (int kt = 0; kt < 4; ++kt) {
    int aoff = (kt * 64 + g * 16) ^ axor;
    short8 a_m = *(const short8*)(amrow + aoff);
    short8 a_x = *(const short8*)(axrow + aoff);
    int nbase = kt * DOUT * 32 + (colbase + cn) * 32 + 8 * g;
#pragma unroll
    for (int ct = 0; ct < NCT; ++ct) {
      int no = nbase + ct * 16 * 32;
      short8 wlh = *(const short8*)(Wb + 0 * MB + no);
      short8 wll = *(const short8*)(Wb + 1 * MB + no);
      short8 wrh = *(const short8*)(Wb + 2 * MB + no);
      short8 wrl = *(const short8*)(Wb + 3 * MB + no);
      acc[ct] = __builtin_amdgcn_mfma_f32_16x16x32_bf16(a_m, wlh, acc[ct], 0, 0, 0);
      acc[ct] = __builtin_amdgcn_mfma_f32_16x16x32_bf16(a_m, wll, acc[ct], 0, 0, 0);
      acc[ct] = __builtin_amdgcn_mfma_f32_16x16x32_bf16(a_x, wrh, acc[ct], 0, 0, 0);
      acc[ct] = __builtin_amdgcn_mfma_f32_16x16x32_bf16(a_x, wrl, acc[ct], 0, 0, 0);
    }
  }

  float p[4];
#pragma unroll
  for (int i = 0; i < 4; ++i) {
    float s = 0.f;
#pragma unroll
    for (int ct = 0; ct < NCT; ++ct) s += acc[ct][i] * acc[ct][i];
#pragma unroll
    for (int m = 1; m < 16; m <<= 1) s += __shfl_xor(s, m);
    p[i] = s;
  }
  if (cn == 0) {
#pragma unroll
    for (int i = 0; i < 4; ++i) ssb[rt * 16 + g * 4 + i][half] = p[i];
  }
  __syncthreads();

#pragma unroll
  for (int i = 0; i < 4; ++i) {
    int rloc = rt * 16 + g * 4 + i;
    int row = base + rloc;
    float ss = ssb[rloc][0] + ssb[rloc][1];
    float rn = 1.0f / fmaxf(sqrtf(ss), 1e-12f);
    if (row < n) {
      ushort_t* op = out + (size_t)row * DOUT + colbase + cn;
#pragma unroll
      for (int ct = 0; ct < NCT; ++ct) op[ct * 16] = f2bf(acc[ct][i] * rn);
    }
  }
}

// ---------------- merged account SAGE: two edge types, one pass, one store ----
// out = l2n(mean1@Wl1+bl1+xd@Wr1) + l2n(mean2@Wl2+bl2+xd@Wr2); xd = src2[row]
template<int DOUT>
__global__ __launch_bounds__(256, 4) void sage2_mfma_kernel(
    const int* __restrict__ rp1, const int* __restrict__ ci1, const ushort_t* __restrict__ src1,
    const int* __restrict__ rp2, const int* __restrict__ ci2, const ushort_t* __restrict__ src2,
    const ushort_t* __restrict__ Wb1, const ushort_t* __restrict__ Wb2,
    const float* __restrict__ bl1, const float* __restrict__ bl2,
    ushort_t* __restrict__ out, int n) {
  constexpr int NCT = DOUT / 32;
  constexpr int MB = 4 * DOUT * 32;
  __shared__ __align__(16) ushort_t a1[32][128];
  __shared__ __align__(16) ushort_t a2[32][128];
  __shared__ __align__(16) ushort_t axl[32][128];
  __shared__ float ssb1[32][2], ssb2[32][2];
  const int tid = threadIdx.x, lane = tid & 63, wv = tid >> 6;
  const int base = blockIdx.x * 32;

  for (int r = wv; r < 32; r += 4) {
    int row = base + r;
    unsigned v1 = 0, v2 = 0, vx = 0;
    if (row < n) {
      {
        int beg = rp1[row], end = rp1[row + 1];
        float s0 = 0.f, s1 = 0.f;
        for (int p = beg; p < end; ++p) {
          unsigned v = ((const unsigned*)(src1 + (size_t)ci1[p] * 128))[lane];
          s0 += __uint_as_float(v << 16);
          s1 += __uint_as_float(v & 0xffff0000u);
        }
        float rc = (end > beg) ? 1.f / (float)(end - beg) : 0.f;
        v1 = (unsigned)f2bf(s0 * rc) | ((unsigned)f2bf(s1 * rc) << 16);
      }
      {
        int beg = rp2[row], end = rp2[row + 1];
        float s0 = 0.f, s1 = 0.f;
        for (int p = beg; p < end; ++p) {
          unsigned v = ((const unsigned*)(src2 + (size_t)ci2[p] * 128))[lane];
          s0 += __uint_as_float(v << 16);
          s1 += __uint_as_float(v & 0xffff0000u);
        }
        float rc = (end > beg) ? 1.f / (float)(end - beg) : 0.f;
        v2 = (unsigned)f2bf(s0 * rc) | ((unsigned)f2bf(s1 * rc) << 16);
      }
      vx = ((const unsigned*)(src2 + (size_t)row * 128))[lane];
    }
    int bo = (lane * 4) ^ ((r & 7) << 4);
    *(unsigned*)((char*)&a1[r][0] + bo) = v1;
    *(unsigned*)((char*)&a2[r][0] + bo) = v2;
    *(unsigned*)((char*)&axl[r][0] + bo) = vx;
  }
  __syncthreads();

  const int rt = wv >> 1, half = wv & 1;
  const int colbase = half * (DOUT / 2);
  const int cn = lane & 15, g = lane >> 4;

  f32x4 acc1[NCT], acc2[NCT];
#pragma unroll
  for (int ct = 0; ct < NCT; ++ct) {
    float b1v = bl1[colbase + ct * 16 + cn];
    float b2v = bl2[colbase + ct * 16 + cn];
    acc1[ct] = (f32x4){b1v, b1v, b1v, b1v};
    acc2[ct] = (f32x4){b2v, b2v, b2v, b2v};
  }

  const int arow = rt * 16 + cn;
  const char* r1 = (const char*)&a1[arow][0];
  const char* r2 = (const char*)&a2[arow][0];
  const char* rx = (const char*)&axl[arow][0];
  const int axor = (arow & 7) << 4;

#pragma unroll
  for (int kt = 0; kt < 4; ++kt) {
    int aoff = (kt * 64 + g * 16) ^ axor;
    short8 f1 = *(const short8*)(r1 + aoff);
    short8 f2 = *(const short8*)(r2 + aoff);
    short8 fx = *(const short8*)(rx + aoff);
    int nbase = kt * DOUT * 32 + (colbase + cn) * 32 + 8 * g;
#pragma unroll
    for (int ct = 0; ct < NCT; ++ct) {
      int no = nbase + ct * 16 * 32;
      {
        short8 wlh = *(const short8*)(Wb1 + 0 * MB + no);
        short8 wll = *(const short8*)(Wb1 + 1 * MB + no);
        short8 wrh = *(const short8*)(Wb1 + 2 * MB + no);
        short8 wrl = *(const short8*)(Wb1 + 3 * MB + no);
        acc1[ct] = __builtin_amdgcn_mfma_f32_16x16x32_bf16(f1, wlh, acc1[ct], 0, 0, 0);
        acc1[ct] = __builtin_amdgcn_mfma_f32_16x16x32_bf16(f1, wll, acc1[ct], 0, 0, 0);
        acc1[ct] = __builtin_amdgcn_mfma_f32_16x16x32_bf16(fx, wrh, acc1[ct], 0, 0, 0);
        acc1[ct] = __builtin_amdgcn_mfma_f32_16x16x32_bf16(fx, wrl, acc1[ct], 0, 0, 0);
      }
      {
        short8 wlh = *(const short8*)(Wb2 + 0 * MB + no);
        short8 wll = *(const short8*)(Wb2 + 1 * MB + no);
        short8 wrh = *(const short8*)(Wb2 + 2 * MB + no);
        short8 wrl = *(const short8*)(Wb2 + 3 * MB + no);
        acc2[ct] = __builtin_amdgcn_mfma_f32_16x16x32_bf16(f2, wlh, acc2[ct], 0, 0, 0);
        acc2[ct] = __builtin_amdgcn_mfma_f32_16x16x32_bf16(f2, wll, acc2[ct], 0, 0, 0);
        acc2[ct] = __builtin_amdgcn_mfma_f32_16x16x32_bf16(fx, wrh, acc2[ct], 0, 0, 0);
        acc2[ct] = __builtin_amdgcn_mfma_f32_16x16x32_bf16(fx, wrl, acc2[ct], 0, 0, 0);
      }
    }
  }

#pragma unroll
  for (int i = 0; i < 4; ++i) {
    float s1 = 0.f, s2 = 0.f;
#pragma unroll
    for (int ct = 0; ct < NCT; ++ct) {
      s1 += acc1[ct][i] * acc1[ct][i];
      s2 += acc2[ct][i] * acc2[ct][i];
    }
#pragma unroll
    for (int m = 1; m < 16; m <<= 1) {
      s1 += __shfl_xor(s1, m);
      s2 += __shfl_xor(s2, m);
    }
    if (cn == 0) {
      ssb1[rt * 16 + g * 4 + i][half] = s1;
      ssb2[rt * 16 + g * 4 + i][half] = s2;
    }
  }
  __syncthreads();

#pragma unroll
  for (int i = 0; i < 4; ++i) {
    int rloc = rt * 16 + g * 4 + i;
    int row = base + rloc;
    float rn1 = 1.0f / fmaxf(sqrtf(ssb1[rloc][0] + ssb1[rloc][1]), 1e-12f);
    float rn2 = 1.0f / fmaxf(sqrtf(ssb2[rloc][0] + ssb2[rloc][1]), 1e-12f);
    if (row < n) {
      ushort_t* op = out + (size_t)row * DOUT + colbase + cn;
#pragma unroll
      for (int ct = 0; ct < NCT; ++ct)
        op[ct * 16] = f2bf(acc1[ct][i] * rn1 + acc2[ct][i] * rn2);
    }
  }
}

// ---------------- BatchNorm (training-mode batch stats) ----------------
template<int C>
__global__ __launch_bounds__(256) void bn_stats_kernel(const __hip_bfloat16* __restrict__ x,
    float* __restrict__ stats, int n) {
  constexpr int RPB = 256 / C;
  int c = threadIdx.x % C;
  float s = 0.f, ss = 0.f;
  for (int r = blockIdx.x * RPB + threadIdx.x / C; r < n; r += gridDim.x * RPB) {
    float v = ldv(x + (size_t)r * C + c);
    s += v; ss += v * v;
  }
  atomicAdd(&stats[c], s);
  atomicAdd(&stats[C + c], ss);
}

template<int C, bool RELU>
__global__ __launch_bounds__(256) void bn_apply_kernel(__hip_bfloat16* __restrict__ x,
    const float* __restrict__ stats, const float* __restrict__ g,
    const float* __restrict__ b, int n) {
  size_t i = (size_t)blockIdx.x * 256 + threadIdx.x;
  size_t total = (size_t)n * C;
  if (i >= total) return;
  int c = (int)(i & (C - 1));
  float rn = 1.f / (float)n;
  float mu = stats[c] * rn;
  float var = stats[C + c] * rn - mu * mu;
  float v = (ldv(&x[i]) - mu) * rsqrtf(var + EPS_BN) * g[c] + b[c];
  if (RELU) v = fmaxf(v, 0.f);
  stv(&x[i], v);
}

// ---------------- classifier via MFMA: out[n] = relu(X@W1.T+b1) @ W2.T + b2 ---
__global__ __launch_bounds__(256, 4) void clf_mfma_kernel(
    const ushort_t* __restrict__ X, const ushort_t* __restrict__ WPc,
    const float* __restrict__ b1, const float* __restrict__ W2,
    const float* __restrict__ b2, float* __restrict__ out, int n) {
  constexpr int HB = 2 * 64 * 32;
  __shared__ __align__(16) ushort_t axl[32][64];
  __shared__ float ssb[32][2];
  const int tid = threadIdx.x, lane = tid & 63, wv = tid >> 6;
  const int base = blockIdx.x * 32;

  for (int r = wv; r < 16; r += 4) {
    int rr = 2 * r + (lane >> 5);
    int row = base + rr;
    int el = lane & 31;
    unsigned v = (row < n) ? ((const unsigned*)(X + (size_t)row * 64))[el] : 0u;
    int swz = (rr & 7) << 4;
    *(unsigned*)((char*)&axl[rr][0] + ((4 * el) ^ swz)) = v;
  }
  __syncthreads();

  const int rt = wv >> 1, half = wv & 1;
  const int colbase = half * 32;
  const int cn = lane & 15, g = lane >> 4;

  f32x4 acc[2];
#pragma unroll
  for (int ct = 0; ct < 2; ++ct) {
    float b = b1[colbase + ct * 16 + cn];
    acc[ct] = (f32x4){b, b, b, b};
  }

  const int arow = rt * 16 + cn;
  const char* rowp = (const char*)&axl[arow][0];
  const int swz = (arow & 7) << 4;

#pragma unroll
  for (int kt = 0; kt < 2; ++kt) {
    short8 a = *(const short8*)(rowp + ((kt * 64 + g * 16) ^ swz));
#pragma unroll
    for (int ct = 0; ct < 2; ++ct) {
      int wb = kt * 64 * 32 + (colbase + ct * 16 + cn) * 32 + 8 * g;
      short8 wh = *(const short8*)(WPc + wb);
      short8 wl = *(const short8*)(WPc + HB + wb);
      acc[ct] = __builtin_amdgcn_mfma_f32_16x16x32_bf16(a, wh, acc[ct], 0, 0, 0);
      acc[ct] = __builtin_amdgcn_mfma_f32_16x16x32_bf16(a, wl, acc[ct], 0, 0, 0);
    }
  }

  float w2v0 = W2[colbase + cn], w2v1 = W2[colbase + 16 + cn];
#pragma unroll
  for (int i = 0; i < 4; ++i) {
    float p = fmaxf(acc[0][i], 0.f) * w2v0 + fmaxf(acc[1][i], 0.f) * w2v1;
#pragma unroll
    for (int m = 1; m < 16; m <<= 1) p += __shfl_xor(p, m);
    if (cn == 0) ssb[rt * 16 + g * 4 + i][half] = p;
  }
  __syncthreads();

  if (tid < 32) {
    int row = base + tid;
    if (row < n) out[row] = ssb[tid][0] + ssb[tid][1] + b2[0];
  }
}

// ---------------- one hetero layer ----------------
template<int DO, bool RELU>
static void run_layer(const ushort_t* WB, const float* bl,
                      const float* g, const float* b,
                      const ushort_t* xa, const ushort_t* xm,
                      ushort_t* oa, ushort_t* om, float* STATS,
                      const int* rp_p, const int* ci_p,
                      const int* rp_r, const int* ci_r,
                      const int* rp_t, const int* ci_t,
                      int NA, int NM, hipStream_t stream) {
  const size_t ETS = (size_t)16 * DO * 32;
  // pays: account -> merchant
  sage_mfma_kernel<DO><<<idiv(NM, 32), 256, 0, stream>>>(
      rp_p, ci_p, xa, xm, WB + 0 * ETS, bl, om, NM);
  // rev_pays + transfer -> account (merged, single pass)
  sage2_mfma_kernel<DO><<<idiv(NA, 32), 256, 0, stream>>>(
      rp_r, ci_r, xm, rp_t, ci_t, xa,
      WB + 1 * ETS, WB + 2 * ETS, bl + DO, bl + 2 * DO, oa, NA);
  // BN account
  hipMemsetAsync(STATS, 0, 2 * DO * sizeof(float), stream);
  bn_stats_kernel<DO><<<1024, 256, 0, stream>>>((const __hip_bfloat16*)oa, STATS, NA);
  bn_apply_kernel<DO, RELU><<<idiv(NA * DO, 256), 256, 0, stream>>>(
      (__hip_bfloat16*)oa, STATS, g, b, NA);
  // BN merchant
  hipMemsetAsync(STATS, 0, 2 * DO * sizeof(float), stream);
  bn_stats_kernel<DO><<<1024, 256, 0, stream>>>((const __hip_bfloat16*)om, STATS, NM);
  bn_apply_kernel<DO, RELU><<<idiv(NM * DO, 256), 256, 0, stream>>>(
      (__hip_bfloat16*)om, STATS, g + DO, b + DO, NM);
}

static size_t ws_need(int NA, int NM, int E) {
  size_t acts = ((size_t)2 * NA * 128 + (size_t)2 * NM * 128) * 2;
  size_t wbuf = ((size_t)2 * 196608 + 98304 + 16384 + 8192 + 8192) * 2;
  size_t stats = 256 * 4;
  size_t ints = ((size_t)(NM + 1) + NM + E
               + 2 * ((size_t)(NA + 1) + NA + E) + 1024) * 4;
  return acts + wbuf + stats + ints + 256;
}

extern "C" void kernel_launch(void* const* d_in, const int* in_sizes, int n_in,
                              void* d_out, int out_size, void* d_ws, size_t ws_size,
                              hipStream_t stream) {
  const int NA = in_sizes[0] / 64;   // 200000
  const int NM = in_sizes[1] / 32;   // 100000
  const int E  = in_sizes[2] / 2;    // 500000
  if (ws_size < ws_need(NA, NM, E)) return;

  const float* x_acc = (const float*)d_in[0];
  const float* x_mer = (const float*)d_in[1];
  const int* ei_pays = (const int*)d_in[2];
  const int* ei_rev  = (const int*)d_in[3];
  const int* ei_tr   = (const int*)d_in[4];
  const float* pWa = (const float*)d_in[5];
  const float* pba = (const float*)d_in[6];
  const float* pWm = (const float*)d_in[7];
  const float* pbm = (const float*)d_in[8];
  const float* Wl[3]  = {(const float*)d_in[9],  (const float*)d_in[12], (const float*)d_in[15]};
  const float* blp[3] = {(const float*)d_in[10], (const float*)d_in[13], (const float*)d_in[16]};
  const float* Wr[3]  = {(const float*)d_in[11], (const float*)d_in[14], (const float*)d_in[17]};
  const float* bng[3] = {(const float*)d_in[18], (const float*)d_in[20], (const float*)d_in[22]};
  const float* bnb[3] = {(const float*)d_in[19], (const float*)d_in[21], (const float*)d_in[23]};
  const float* cW1 = (const float*)d_in[24];
  const float* cb1 = (const float*)d_in[25];
  const float* cW2 = (const float*)d_in[26];
  const float* cb2 = (const float*)d_in[27];

  char* p = (char*)d_ws;
  ushort_t* A0 = (ushort_t*)p; p += (size_t)NA * 128 * 2;
  ushort_t* A1 = (ushort_t*)p; p += (size_t)NA * 128 * 2;
  ushort_t* M0 = (ushort_t*)p; p += (size_t)NM * 128 * 2;
  ushort_t* M1 = (ushort_t*)p; p += (size_t)NM * 128 * 2;
  ushort_t* WB0 = (ushort_t*)p; p += (size_t)196608 * 2;
  ushort_t* WB1 = (ushort_t*)p; p += (size_t)196608 * 2;
  ushort_t* WB2 = (ushort_t*)p; p += (size_t)98304 * 2;
  ushort_t* WPA = (ushort_t*)p; p += (size_t)16384 * 2;
  ushort_t* WPM = (ushort_t*)p; p += (size_t)8192 * 2;
  ushort_t* WPC = (ushort_t*)p; p += (size_t)8192 * 2;
  p = (char*)(((uintptr_t)p + 15) & ~(uintptr_t)15);
  float* STATS = (float*)p; p += 256 * 4;
  int* rp_p  = (int*)p; p += ((size_t)NM + 1) * 4;
  int* cur_p = (int*)p; p += (size_t)NM * 4;
  int* ci_p  = (int*)p; p += (size_t)E * 4;
  int* rp_r  = (int*)p; p += ((size_t)NA + 1) * 4;
  int* cur_r = (int*)p; p += (size_t)NA * 4;
  int* ci_r  = (int*)p; p += (size_t)E * 4;
  int* rp_t  = (int*)p; p += ((size_t)NA + 1) * 4;
  int* cur_t = (int*)p; p += (size_t)NA * 4;
  int* ci_t  = (int*)p; p += (size_t)E * 4;
  int* bsum  = (int*)p; p += 1024 * 4;

  // ---- CSR builds (cur doubles as count buffer, then cursor) ----
  struct ET { const int* ei; int nd; int* rp; int* cur; int* ci; };
  ET et[3] = {
      {ei_pays, NM, rp_p, cur_p, ci_p},
      {ei_rev,  NA, rp_r, cur_r, ci_r},
      {ei_tr,   NA, rp_t, cur_t, ci_t},
  };
  for (int t = 0; t < 3; ++t) {
    hipMemsetAsync(et[t].cur, 0, (size_t)et[t].nd * sizeof(int), stream);
    cnt_kernel<<<idiv(E, 256), 256, 0, stream>>>(et[t].ei, et[t].cur, E);
    int nb = idiv(et[t].nd, SCAN_EPB);
    bsum_kernel<<<nb, SCAN_TPB, 0, stream>>>(et[t].cur, bsum, et[t].nd);
    bscan_kernel<<<1, 1024, 0, stream>>>(bsum, nb);
    scatter_scan_kernel<<<nb, SCAN_TPB, 0, stream>>>(et[t].cur, bsum, et[t].rp,
                                                     et[t].nd, E);
    fill_kernel<<<idiv(E, 256), 256, 0, stream>>>(et[t].ei, et[t].cur, et[t].ci, E);
  }

  // ---- W conversions ----
  wprep_kernel<<<idiv(3 * 2 * 128 * 128, 256), 256, 0, stream>>>(Wl[0], Wr[0], WB0, 128);
  wprep_kernel<<<idiv(3 * 2 * 128 * 128, 256), 256, 0, stream>>>(Wl[1], Wr[1], WB1, 128);
  wprep_kernel<<<idiv(3 * 2 * 64 * 128, 256), 256, 0, stream>>>(Wl[2], Wr[2], WB2, 64);
  wprep_one_kernel<<<idiv(128 * 64, 256), 256, 0, stream>>>(pWa, WPA, 128, 64);
  wprep_one_kernel<<<idiv(128 * 32, 256), 256, 0, stream>>>(pWm, WPM, 128, 32);
  wprep_one_kernel<<<idiv(64 * 64, 256), 256, 0, stream>>>(cW1, WPC, 64, 64);

  // ---- input projections (MFMA) ----
  proj_mfma_kernel<64><<<idiv(NA, 32), 256, 0, stream>>>(x_acc, WPA, pba, A0, NA);
  proj_mfma_kernel<32><<<idiv(NM, 32), 256, 0, stream>>>(x_mer, WPM, pbm, M0, NM);

  // ---- 3 hetero layers ----
  ushort_t *xa = A0, *xm = M0, *oa = A1, *om = M1;
  run_layer<128, true>(WB0, blp[0], bng[0], bnb[0], xa, xm, oa, om, STATS,
                       rp_p, ci_p, rp_r, ci_r, rp_t, ci_t, NA, NM, stream);
  { ushort_t* t = xa; xa = oa; oa = t; t = xm; xm = om; om = t; }
  run_layer<128, true>(WB1, blp[1], bng[1], bnb[1], xa, xm, oa, om, STATS,
                       rp_p, ci_p, rp_r, ci_r, rp_t, ci_t, NA, NM, stream);
  { ushort_t* t = xa; xa = oa; oa = t; t = xm; xm = om; om = t; }
  run_layer<64, false>(WB2, blp[2], bng[2], bnb[2], xa, xm, oa, om, STATS,
                       rp_p, ci_p, rp_r, ci_r, rp_t, ci_t, NA, NM, stream);
  { ushort_t* t = xa; xa = oa; oa = t; t = xm; xm = om; om = t; }

  // ---- classifier head on accounts (MFMA) ----
  clf_mfma_kernel<<<idiv(NA, 32), 256, 0, stream>>>(xa, WPC, cb1, cW2, cb2,
                                                    (float*)d_out, NA);
}

// Round 6
// 1828.755 us; speedup vs baseline: 2.8720x; 1.1456x over previous
//
#include <hip/hip_runtime.h>
#include <hip/hip_bf16.h>
#include <cstdint>
#include <cstddef>

#define EPS_BN 1e-5f

typedef unsigned short ushort_t;
typedef __attribute__((ext_vector_type(8))) short short8;
typedef __attribute__((ext_vector_type(4))) float f32x4;

static inline int idiv(int a, int b) { return (a + b - 1) / b; }

__device__ __forceinline__ float ldv(const __hip_bfloat16* p) { return __bfloat162float(*p); }
__device__ __forceinline__ void stv(__hip_bfloat16* p, float v) { *p = __float2bfloat16(v); }

__device__ __forceinline__ ushort_t f2bf(float x) {
  __hip_bfloat16 h = __float2bfloat16(x);
  return *reinterpret_cast<ushort_t*>(&h);
}
__device__ __forceinline__ float bf2f(ushort_t u) {
  unsigned v = (unsigned)u << 16;
  return __uint_as_float(v);
}
__device__ __forceinline__ float bflo(unsigned u) { return __uint_as_float(u << 16); }
__device__ __forceinline__ float bfhi(unsigned u) { return __uint_as_float(u & 0xffff0000u); }

// ---------------- CSR build ----------------
__global__ void cnt_kernel(const int* __restrict__ ei, int* __restrict__ cnt, int E) {
  int e = blockIdx.x * 256 + threadIdx.x;
  if (e < E) atomicAdd(&cnt[ei[E + e]], 1);
}

#define SCAN_TPB 256
#define SCAN_EPT 16
#define SCAN_EPB (SCAN_TPB * SCAN_EPT)

__global__ __launch_bounds__(SCAN_TPB) void bsum_kernel(const int* __restrict__ cnt,
                                                        int* __restrict__ bsum, int n) {
  __shared__ int sm[SCAN_TPB];
  int lo = blockIdx.x * SCAN_EPB + threadIdx.x * SCAN_EPT;
  int s = 0;
#pragma unroll
  for (int i = 0; i < SCAN_EPT; ++i) { int idx = lo + i; if (idx < n) s += cnt[idx]; }
  sm[threadIdx.x] = s;
  __syncthreads();
  for (int off = SCAN_TPB / 2; off; off >>= 1) {
    if (threadIdx.x < off) sm[threadIdx.x] += sm[threadIdx.x + off];
    __syncthreads();
  }
  if (threadIdx.x == 0) bsum[blockIdx.x] = sm[0];
}

__global__ __launch_bounds__(1024) void bscan_kernel(int* __restrict__ bsum, int nb) {
  __shared__ int sm[1024];
  int t = threadIdx.x;
  int v = (t < nb) ? bsum[t] : 0;
  sm[t] = v;
  __syncthreads();
  for (int off = 1; off < 1024; off <<= 1) {
    int u = (t >= off) ? sm[t - off] : 0;
    __syncthreads();
    sm[t] += u;
    __syncthreads();
  }
  if (t < nb) bsum[t] = sm[t] - v;  // exclusive
}

__global__ __launch_bounds__(SCAN_TPB) void scatter_scan_kernel(
    int* cntcur, const int* __restrict__ bsum,
    int* __restrict__ row_ptr, int n, int total) {
  __shared__ int sm[SCAN_TPB];
  int t = threadIdx.x;
  int lo = blockIdx.x * SCAN_EPB + t * SCAN_EPT;
  int loc[SCAN_EPT];
  int s = 0;
#pragma unroll
  for (int i = 0; i < SCAN_EPT; ++i) {
    int idx = lo + i;
    int c = (idx < n) ? cntcur[idx] : 0;
    loc[i] = s; s += c;
  }
  sm[t] = s;
  __syncthreads();
  for (int off = 1; off < SCAN_TPB; off <<= 1) {
    int u = (t >= off) ? sm[t - off] : 0;
    __syncthreads();
    sm[t] += u;
    __syncthreads();
  }
  int base = sm[t] - s + bsum[blockIdx.x];
#pragma unroll
  for (int i = 0; i < SCAN_EPT; ++i) {
    int idx = lo + i;
    if (idx < n) { int v = base + loc[i]; row_ptr[idx] = v; cntcur[idx] = v; }
  }
  if (blockIdx.x == 0 && t == 0) row_ptr[n] = total;
}

__global__ void fill_kernel(const int* __restrict__ ei, int* __restrict__ cursor,
                            int* __restrict__ col_idx, int E) {
  int e = blockIdx.x * 256 + threadIdx.x;
  if (e < E) {
    int d = ei[E + e];
    int p = atomicAdd(&cursor[d], 1);
    col_idx[p] = ei[e];
  }
}

// ---------------- W prep (sage): fp32 [3][DOUT][128] (Wl,Wr) -> bf16 hi/lo k-tiled
__global__ void wprep_kernel(const float* __restrict__ Wl, const float* __restrict__ Wr,
                             ushort_t* __restrict__ dst, int DOUT) {
  int idx = blockIdx.x * 256 + threadIdx.x;
  int per_mat = DOUT * 128;
  int total = 3 * 2 * per_mat;
  if (idx >= total) return;
  int et = idx / (2 * per_mat);
  int r = idx % (2 * per_mat);
  int mat = r / per_mat;
  int e = r % per_mat;
  int nrow = e / 128, k = e % 128;
  const float* src = mat ? Wr : Wl;
  float w = src[et * per_mat + nrow * 128 + k];
  ushort_t hi = f2bf(w);
  ushort_t lo = f2bf(w - bf2f(hi));
  int kt = k >> 5, kk = k & 31;
  int pos = kt * DOUT * 32 + nrow * 32 + kk;
  size_t etbase = (size_t)et * (16 * DOUT * 32);
  int MB = 4 * DOUT * 32;
  dst[etbase + (size_t)(mat * 2 + 0) * MB + pos] = hi;
  dst[etbase + (size_t)(mat * 2 + 1) * MB + pos] = lo;
}

// ---------------- W prep (single matrix [DOUT][K]) -> [hilo(2)][kt][DOUT][32] ----
__global__ void wprep_one_kernel(const float* __restrict__ W, ushort_t* __restrict__ dst,
                                 int DOUT, int K) {
  int idx = blockIdx.x * 256 + threadIdx.x;
  if (idx >= DOUT * K) return;
  int row = idx / K, k = idx % K;
  float w = W[idx];
  ushort_t hi = f2bf(w);
  ushort_t lo = f2bf(w - bf2f(hi));
  int kt = k >> 5, kk = k & 31;
  int HB = (K >> 5) * DOUT * 32;
  int pos = kt * DOUT * 32 + row * 32 + kk;
  dst[pos] = hi;
  dst[HB + pos] = lo;
}

// ---------------- input projection via MFMA: out[n][128] = X[n][K] @ W.T + b ----
template<int K>
__global__ __launch_bounds__(256, 4) void proj_mfma_kernel(
    const float* __restrict__ X, const ushort_t* __restrict__ WP,
    const float* __restrict__ bias, ushort_t* __restrict__ out, int n) {
  constexpr int KT = K / 32;
  constexpr int HB = KT * 128 * 32;
  __shared__ __align__(16) ushort_t ah[32][2 * K];  // [hi | lo] per row
  const int tid = threadIdx.x, lane = tid & 63, wv = tid >> 6;
  const int base = blockIdx.x * 32;

  if (K == 64) {
    for (int r = wv; r < 32; r += 4) {
      int row = base + r;
      float v = (row < n) ? X[(size_t)row * 64 + lane] : 0.f;
      ushort_t hi = f2bf(v);
      ushort_t lo = f2bf(v - bf2f(hi));
      char* rp = (char*)&ah[r][0];
      int swz = (r & 7) << 4;
      *(ushort_t*)(rp + ((2 * lane) ^ swz)) = hi;
      *(ushort_t*)(rp + ((2 * K + 2 * lane) ^ swz)) = lo;
    }
  } else {
    for (int r = wv; r < 16; r += 4) {
      int rr = 2 * r + (lane >> 5);
      int row = base + rr;
      int el = lane & 31;
      float v = (row < n) ? X[(size_t)row * K + el] : 0.f;
      ushort_t hi = f2bf(v);
      ushort_t lo = f2bf(v - bf2f(hi));
      char* rp = (char*)&ah[rr][0];
      int swz = (rr & 7) << 4;
      *(ushort_t*)(rp + ((2 * el) ^ swz)) = hi;
      *(ushort_t*)(rp + ((2 * K + 2 * el) ^ swz)) = lo;
    }
  }
  __syncthreads();

  const int rt = wv >> 1, half = wv & 1;
  const int colbase = half * 64;
  const int cn = lane & 15, g = lane >> 4;

  f32x4 acc[4];
#pragma unroll
  for (int ct = 0; ct < 4; ++ct) {
    float b = bias[colbase + ct * 16 + cn];
    acc[ct] = (f32x4){b, b, b, b};
  }

  const int arow = rt * 16 + cn;
  const char* rowp = (const char*)&ah[arow][0];
  const int swz = (arow & 7) << 4;

#pragma unroll
  for (int kt = 0; kt < KT; ++kt) {
    int hb = kt * 64 + g * 16;
    short8 a_h = *(const short8*)(rowp + (hb ^ swz));
    short8 a_l = *(const short8*)(rowp + ((2 * K + hb) ^ swz));
#pragma unroll
    for (int ct = 0; ct < 4; ++ct) {
      int wb = kt * 128 * 32 + (colbase + ct * 16 + cn) * 32 + 8 * g;
      short8 wh = *(const short8*)(WP + wb);
      short8 wl = *(const short8*)(WP + HB + wb);
      acc[ct] = __builtin_amdgcn_mfma_f32_16x16x32_bf16(a_h, wh, acc[ct], 0, 0, 0);
      acc[ct] = __builtin_amdgcn_mfma_f32_16x16x32_bf16(a_h, wl, acc[ct], 0, 0, 0);
      acc[ct] = __builtin_amdgcn_mfma_f32_16x16x32_bf16(a_l, wh, acc[ct], 0, 0, 0);
    }
  }

#pragma unroll
  for (int i = 0; i < 4; ++i) {
    int rloc = rt * 16 + g * 4 + i;
    int row = base + rloc;
    if (row < n) {
      ushort_t* op = out + (size_t)row * 128 + colbase + cn;
#pragma unroll
      for (int ct = 0; ct < 4; ++ct) op[ct * 16] = f2bf(acc[ct][i]);
    }
  }
}

// ---- 4-way neighbor-parallel gather: group gq of 16 lanes loads whole rows ----
// s[8] accumulates cols {wq*8 .. wq*8+7}; returns neighbor count.
__device__ __forceinline__ int gather4(const int* __restrict__ rp,
                                       const int* __restrict__ ci,
                                       const ushort_t* __restrict__ src,
                                       int row, int gq, int wq, float* s) {
  int beg = rp[row], end = rp[row + 1];
  for (int p = beg + gq; p < end; p += 4) {
    uint4 v = ((const uint4*)(src + (size_t)ci[p] * 128))[wq];
    s[0] += bflo(v.x); s[1] += bfhi(v.x);
    s[2] += bflo(v.y); s[3] += bfhi(v.y);
    s[4] += bflo(v.z); s[5] += bfhi(v.z);
    s[6] += bflo(v.w); s[7] += bfhi(v.w);
  }
  return end - beg;
}

__device__ __forceinline__ uint4 pack_bf8(const float* s, float rc) {
  uint4 o;
  o.x = (unsigned)f2bf(s[0] * rc) | ((unsigned)f2bf(s[1] * rc) << 16);
  o.y = (unsigned)f2bf(s[2] * rc) | ((unsigned)f2bf(s[3] * rc) << 16);
  o.z = (unsigned)f2bf(s[4] * rc) | ((unsigned)f2bf(s[5] * rc) << 16);
  o.w = (unsigned)f2bf(s[6] * rc) | ((unsigned)f2bf(s[7] * rc) << 16);
  return o;
}

// ---------------- fused SAGE via MFMA (single edge type) ----------
template<int DOUT>
__global__ __launch_bounds__(256, 4) void sage_mfma_kernel(
    const int* __restrict__ row_ptr, const int* __restrict__ col_idx,
    const ushort_t* __restrict__ xsrc, const ushort_t* __restrict__ xd,
    const ushort_t* __restrict__ Wb, const float* __restrict__ bl,
    ushort_t* __restrict__ out, int n) {
  constexpr int NCT = DOUT / 32;
  constexpr int MB = 4 * DOUT * 32;
  __shared__ __align__(16) ushort_t am[32][128];
  __shared__ __align__(16) ushort_t ax[32][128];
  __shared__ float ssb[32][2];
  const int tid = threadIdx.x, lane = tid & 63, wv = tid >> 6;
  const int gq = lane >> 4, wq = lane & 15;
  const int base = blockIdx.x * 32;

  for (int r = wv; r < 32; r += 4) {
    int row = base + r;
    float s[8] = {0.f, 0.f, 0.f, 0.f, 0.f, 0.f, 0.f, 0.f};
    uint4 xv = {0u, 0u, 0u, 0u};
    int cnt = 0;
    if (row < n) {
      if (gq == 1) xv = ((const uint4*)(xd + (size_t)row * 128))[wq];
      cnt = gather4(row_ptr, col_idx, xsrc, row, gq, wq, s);
    }
#pragma unroll
    for (int j = 0; j < 8; ++j) {
      s[j] += __shfl_xor(s[j], 16);
      s[j] += __shfl_xor(s[j], 32);
    }
    float rc = (cnt > 0) ? 1.f / (float)cnt : 0.f;
    int bo = (wq * 16) ^ ((r & 7) << 4);
    if (gq == 0) *(uint4*)((char*)&am[r][0] + bo) = pack_bf8(s, rc);
    else if (gq == 1) *(uint4*)((char*)&ax[r][0] + bo) = xv;
  }
  __syncthreads();

  const int rt = wv >> 1, half = wv & 1;
  const int colbase = half * (DOUT / 2);
  const int cn = lane & 15, g = lane >> 4;

  f32x4 acc[NCT];
#pragma unroll
  for (int ct = 0; ct < NCT; ++ct) {
    float b = bl[colbase + ct * 16 + cn];
    acc[ct] = (f32x4){b, b, b, b};
  }

  const int arow = rt * 16 + cn;
  const char* amrow = (const char*)&am[arow][0];
  const char* axrow = (const char*)&ax[arow][0];
  const int axor = (arow & 7) << 4;

#pragma unroll
  for (int kt = 0; kt < 4; ++kt) {
    int aoff = (kt * 64 + g * 16) ^ axor;
    short8 a_m = *(const short8*)(amrow + aoff);
    short8 a_x = *(const short8*)(axrow + aoff);
    int nbase = kt * DOUT * 32 + (colbase + cn) * 32 + 8 * g;
#pragma unroll
    for (int ct = 0; ct < NCT; ++ct) {
      int no = nbase + ct * 16 * 32;
      short8 wlh = *(const short8*)(Wb + 0 * MB + no);
      short8 wll = *(const short8*)(Wb + 1 * MB + no);
      short8 wrh = *(const short8*)(Wb + 2 * MB + no);
      short8 wrl = *(const short8*)(Wb + 3 * MB + no);
      acc[ct] = __builtin_amdgcn_mfma_f32_16x16x32_bf16(a_m, wlh, acc[ct], 0, 0, 0);
      acc[ct] = __builtin_amdgcn_mfma_f32_16x16x32_bf16(a_m, wll, acc[ct], 0, 0, 0);
      acc[ct] = __builtin_amdgcn_mfma_f32_16x16x32_bf16(a_x, wrh, acc[ct], 0, 0, 0);
      acc[ct] = __builtin_amdgcn_mfma_f32_16x16x32_bf16(a_x, wrl, acc[ct], 0, 0, 0);
    }
  }

  float p[4];
#pragma unroll
  for (int i = 0; i < 4; ++i) {
    float s = 0.f;
#pragma unroll
    for (int ct = 0; ct < NCT; ++ct) s += acc[ct][i] * acc[ct][i];
#pragma unroll
    for (int m = 1; m < 16; m <<= 1) s += __shfl_xor(s, m);
    p[i] = s;
  }
  if (cn == 0) {
#pragma unroll
    for (int i = 0; i < 4; ++i) ssb[rt * 16 + g * 4 + i][half] = p[i];
  }
  __syncthreads();

#pragma unroll
  for (int i = 0; i < 4; ++i) {
    int rloc = rt * 16 + g * 4 + i;
    int row = base + rloc;
    float ss = ssb[rloc][0] + ssb[rloc][1];
    float rn = 1.0f / fmaxf(sqrtf(ss), 1e-12f);
    if (row < n) {
      ushort_t* op = out + (size_t)row * DOUT + colbase + cn;
#pragma unroll
      for (int ct = 0; ct < NCT; ++ct) op[ct * 16] = f2bf(acc[ct][i] * rn);
    }
  }
}

// ---------------- merged account SAGE: two edge types, one pass, one store ----
template<int DOUT>
__global__ __launch_bounds__(256, 4) void sage2_mfma_kernel(
    const int* __restrict__ rp1, const int* __restrict__ ci1, const ushort_t* __restrict__ src1,
    const int* __restrict__ rp2, const int* __restrict__ ci2, const ushort_t* __restrict__ src2,
    const ushort_t* __restrict__ Wb1, const ushort_t* __restrict__ Wb2,
    const float* __restrict__ bl1, const float* __restrict__ bl2,
    ushort_t* __restrict__ out, int n) {
  constexpr int NCT = DOUT / 32;
  constexpr int MB = 4 * DOUT * 32;
  __shared__ __align__(16) ushort_t a1[32][128];
  __shared__ __align__(16) ushort_t a2[32][128];
  __shared__ __align__(16) ushort_t axl[32][128];
  __shared__ float ssb1[32][2], ssb2[32][2];
  const int tid = threadIdx.x, lane = tid & 63, wv = tid >> 6;
  const int gq = lane >> 4, wq = lane & 15;
  const int base = blockIdx.x * 32;

  for (int r = wv; r < 32; r += 4) {
    int row = base + r;
    float s1[8] = {0.f, 0.f, 0.f, 0.f, 0.f, 0.f, 0.f, 0.f};
    float s2[8] = {0.f, 0.f, 0.f, 0.f, 0.f, 0.f, 0.f, 0.f};
    uint4 xv = {0u, 0u, 0u, 0u};
    int c1 = 0, c2 = 0;
    if (row < n) {
      if (gq == 1) xv = ((const uint4*)(src2 + (size_t)row * 128))[wq];
      c1 = gather4(rp1, ci1, src1, row, gq, wq, s1);
      c2 = gather4(rp2, ci2, src2, row, gq, wq, s2);
    }
#pragma unroll
    for (int j = 0; j < 8; ++j) {
      s1[j] += __shfl_xor(s1[j], 16);
      s1[j] += __shfl_xor(s1[j], 32);
      s2[j] += __shfl_xor(s2[j], 16);
      s2[j] += __shfl_xor(s2[j], 32);
    }
    float rc1 = (c1 > 0) ? 1.f / (float)c1 : 0.f;
    float rc2 = (c2 > 0) ? 1.f / (float)c2 : 0.f;
    int bo = (wq * 16) ^ ((r & 7) << 4);
    if (gq == 0) *(uint4*)((char*)&a1[r][0] + bo) = pack_bf8(s1, rc1);
    else if (gq == 2) *(uint4*)((char*)&a2[r][0] + bo) = pack_bf8(s2, rc2);
    else if (gq == 1) *(uint4*)((char*)&axl[r][0] + bo) = xv;
  }
  __syncthreads();

  const int rt = wv >> 1, half = wv & 1;
  const int colbase = half * (DOUT / 2);
  const int cn = lane & 15, g = lane >> 4;

  f32x4 acc1[NCT], acc2[NCT];
#pragma unroll
  for (int ct = 0; ct < NCT; ++ct) {
    float b1v = bl1[colbase + ct * 16 + cn];
    float b2v = bl2[colbase + ct * 16 + cn];
    acc1[ct] = (f32x4){b1v, b1v, b1v, b1v};
    acc2[ct] = (f32x4){b2v, b2v, b2v, b2v};
  }

  const int arow = rt * 16 + cn;
  const char* r1 = (const char*)&a1[arow][0];
  const char* r2 = (const char*)&a2[arow][0];
  const char* rx = (const char*)&axl[arow][0];
  const int axor = (arow & 7) << 4;

#pragma unroll
  for (int kt = 0; kt < 4; ++kt) {
    int aoff = (kt * 64 + g * 16) ^ axor;
    short8 f1 = *(const short8*)(r1 + aoff);
    short8 f2 = *(const short8*)(r2 + aoff);
    short8 fx = *(const short8*)(rx + aoff);
    int nbase = kt * DOUT * 32 + (colbase + cn) * 32 + 8 * g;
#pragma unroll
    for (int ct = 0; ct < NCT; ++ct) {
      int no = nbase + ct * 16 * 32;
      {
        short8 wlh = *(const short8*)(Wb1 + 0 * MB + no);
        short8 wll = *(const short8*)(Wb1 + 1 * MB + no);
        short8 wrh = *(const short8*)(Wb1 + 2 * MB + no);
        short8 wrl = *(const short8*)(Wb1 + 3 * MB + no);
        acc1[ct] = __builtin_amdgcn_mfma_f32_16x16x32_bf16(f1, wlh, acc1[ct], 0, 0, 0);
        acc1[ct] = __builtin_amdgcn_mfma_f32_16x16x32_bf16(f1, wll, acc1[ct], 0, 0, 0);
        acc1[ct] = __builtin_amdgcn_mfma_f32_16x16x32_bf16(fx, wrh, acc1[ct], 0, 0, 0);
        acc1[ct] = __builtin_amdgcn_mfma_f32_16x16x32_bf16(fx, wrl, acc1[ct], 0, 0, 0);
      }
      {
        short8 wlh = *(const short8*)(Wb2 + 0 * MB + no);
        short8 wll = *(const short8*)(Wb2 + 1 * MB + no);
        short8 wrh = *(const short8*)(Wb2 + 2 * MB + no);
        short8 wrl = *(const short8*)(Wb2 + 3 * MB + no);
        acc2[ct] = __builtin_amdgcn_mfma_f32_16x16x32_bf16(f2, wlh, acc2[ct], 0, 0, 0);
        acc2[ct] = __builtin_amdgcn_mfma_f32_16x16x32_bf16(f2, wll, acc2[ct], 0, 0, 0);
        acc2[ct] = __builtin_amdgcn_mfma_f32_16x16x32_bf16(fx, wrh, acc2[ct], 0, 0, 0);
        acc2[ct] = __builtin_amdgcn_mfma_f32_16x16x32_bf16(fx, wrl, acc2[ct], 0, 0, 0);
      }
    }
  }

#pragma unroll
  for (int i = 0; i < 4; ++i) {
    float s1 = 0.f, s2 = 0.f;
#pragma unroll
    for (int ct = 0; ct < NCT; ++ct) {
      s1 += acc1[ct][i] * acc1[ct][i];
      s2 += acc2[ct][i] * acc2[ct][i];
    }
#pragma unroll
    for (int m = 1; m < 16; m <<= 1) {
      s1 += __shfl_xor(s1, m);
      s2 += __shfl_xor(s2, m);
    }
    if (cn == 0) {
      ssb1[rt * 16 + g * 4 + i][half] = s1;
      ssb2[rt * 16 + g * 4 + i][half] = s2;
    }
  }
  __syncthreads();

#pragma unroll
  for (int i = 0; i < 4; ++i) {
    int rloc = rt * 16 + g * 4 + i;
    int row = base + rloc;
    float rn1 = 1.0f / fmaxf(sqrtf(ssb1[rloc][0] + ssb1[rloc][1]), 1e-12f);
    float rn2 = 1.0f / fmaxf(sqrtf(ssb2[rloc][0] + ssb2[rloc][1]), 1e-12f);
    if (row < n) {
      ushort_t* op = out + (size_t)row * DOUT + colbase + cn;
#pragma unroll
      for (int ct = 0; ct < NCT; ++ct)
        op[ct * 16] = f2bf(acc1[ct][i] * rn1 + acc2[ct][i] * rn2);
    }
  }
}

// ---------------- BatchNorm (training-mode batch stats) ----------------
template<int C>
__global__ __launch_bounds__(256) void bn_stats_kernel(const __hip_bfloat16* __restrict__ x,
    float* __restrict__ stats, int n) {
  constexpr int RPB = 256 / C;
  int c = threadIdx.x % C;
  float s = 0.f, ss = 0.f;
  for (int r = blockIdx.x * RPB + threadIdx.x / C; r < n; r += gridDim.x * RPB) {
    float v = ldv(x + (size_t)r * C + c);
    s += v; ss += v * v;
  }
  atomicAdd(&stats[c], s);
  atomicAdd(&stats[C + c], ss);
}

template<int C, bool RELU>
__global__ __launch_bounds__(256) void bn_apply_kernel(__hip_bfloat16* __restrict__ x,
    const float* __restrict__ stats, const float* __restrict__ g,
    const float* __restrict__ b, int n) {
  size_t i = (size_t)blockIdx.x * 256 + threadIdx.x;
  size_t total = (size_t)n * C;
  if (i >= total) return;
  int c = (int)(i & (C - 1));
  float rn = 1.f / (float)n;
  float mu = stats[c] * rn;
  float var = stats[C + c] * rn - mu * mu;
  float v = (ldv(&x[i]) - mu) * rsqrtf(var + EPS_BN) * g[c] + b[c];
  if (RELU) v = fmaxf(v, 0.f);
  stv(&x[i], v);
}

// ---------------- classifier via MFMA: out[n] = relu(X@W1.T+b1) @ W2.T + b2 ---
__global__ __launch_bounds__(256, 4) void clf_mfma_kernel(
    const ushort_t* __restrict__ X, const ushort_t* __restrict__ WPc,
    const float* __restrict__ b1, const float* __restrict__ W2,
    const float* __restrict__ b2, float* __restrict__ out, int n) {
  constexpr int HB = 2 * 64 * 32;
  __shared__ __align__(16) ushort_t axl[32][64];
  __shared__ float ssb[32][2];
  const int tid = threadIdx.x, lane = tid & 63, wv = tid >> 6;
  const int base = blockIdx.x * 32;

  for (int r = wv; r < 16; r += 4) {
    int rr = 2 * r + (lane >> 5);
    int row = base + rr;
    int el = lane & 31;
    unsigned v = (row < n) ? ((const unsigned*)(X + (size_t)row * 64))[el] : 0u;
    int swz = (rr & 7) << 4;
    *(unsigned*)((char*)&axl[rr][0] + ((4 * el) ^ swz)) = v;
  }
  __syncthreads();

  const int rt = wv >> 1, half = wv & 1;
  const int colbase = half * 32;
  const int cn = lane & 15, g = lane >> 4;

  f32x4 acc[2];
#pragma unroll
  for (int ct = 0; ct < 2; ++ct) {
    float b = b1[colbase + ct * 16 + cn];
    acc[ct] = (f32x4){b, b, b, b};
  }

  const int arow = rt * 16 + cn;
  const char* rowp = (const char*)&axl[arow][0];
  const int swz = (arow & 7) << 4;

#pragma unroll
  for (int kt = 0; kt < 2; ++kt) {
    short8 a = *(const short8*)(rowp + ((kt * 64 + g * 16) ^ swz));
#pragma unroll
    for (int ct = 0; ct < 2; ++ct) {
      int wb = kt * 64 * 32 + (colbase + ct * 16 + cn) * 32 + 8 * g;
      short8 wh = *(const short8*)(WPc + wb);
      short8 wl = *(const short8*)(WPc + HB + wb);
      acc[ct] = __builtin_amdgcn_mfma_f32_16x16x32_bf16(a, wh, acc[ct], 0, 0, 0);
      acc[ct] = __builtin_amdgcn_mfma_f32_16x16x32_bf16(a, wl, acc[ct], 0, 0, 0);
    }
  }

  float w2v0 = W2[colbase + cn], w2v1 = W2[colbase + 16 + cn];
#pragma unroll
  for (int i = 0; i < 4; ++i) {
    float p = fmaxf(acc[0][i], 0.f) * w2v0 + fmaxf(acc[1][i], 0.f) * w2v1;
#pragma unroll
    for (int m = 1; m < 16; m <<= 1) p += __shfl_xor(p, m);
    if (cn == 0) ssb[rt * 16 + g * 4 + i][half] = p;
  }
  __syncthreads();

  if (tid < 32) {
    int row = base + tid;
    if (row < n) out[row] = ssb[tid][0] + ssb[tid][1] + b2[0];
  }
}

// ---------------- one hetero layer ----------------
template<int DO, bool RELU>
static void run_layer(const ushort_t* WB, const float* bl,
                      const float* g, const float* b,
                      const ushort_t* xa, const ushort_t* xm,
                      ushort_t* oa, ushort_t* om, float* STATS,
                      const int* rp_p, const int* ci_p,
                      const int* rp_r, const int* ci_r,
                      const int* rp_t, const int* ci_t,
                      int NA, int NM, hipStream_t stream) {
  const size_t ETS = (size_t)16 * DO * 32;
  // pays: account -> merchant
  sage_mfma_kernel<DO><<<idiv(NM, 32), 256, 0, stream>>>(
      rp_p, ci_p, xa, xm, WB + 0 * ETS, bl, om, NM);
  // rev_pays + transfer -> account (merged, single pass)
  sage2_mfma_kernel<DO><<<idiv(NA, 32), 256, 0, stream>>>(
      rp_r, ci_r, xm, rp_t, ci_t, xa,
      WB + 1 * ETS, WB + 2 * ETS, bl + DO, bl + 2 * DO, oa, NA);
  // BN account
  hipMemsetAsync(STATS, 0, 2 * DO * sizeof(float), stream);
  bn_stats_kernel<DO><<<256, 256, 0, stream>>>((const __hip_bfloat16*)oa, STATS, NA);
  bn_apply_kernel<DO, RELU><<<idiv(NA * DO, 256), 256, 0, stream>>>(
      (__hip_bfloat16*)oa, STATS, g, b, NA);
  // BN merchant
  hipMemsetAsync(STATS, 0, 2 * DO * sizeof(float), stream);
  bn_stats_kernel<DO><<<256, 256, 0, stream>>>((const __hip_bfloat16*)om, STATS, NM);
  bn_apply_kernel<DO, RELU><<<idiv(NM * DO, 256), 256, 0, stream>>>(
      (__hip_bfloat16*)om, STATS, g + DO, b + DO, NM);
}

static size_t ws_need(int NA, int NM, int E) {
  size_t acts = ((size_t)2 * NA * 128 + (size_t)2 * NM * 128) * 2;
  size_t wbuf = ((size_t)2 * 196608 + 98304 + 16384 + 8192 + 8192) * 2;
  size_t stats = 256 * 4;
  size_t ints = ((size_t)(NM + 1) + NM + E
               + 2 * ((size_t)(NA + 1) + NA + E) + 1024) * 4;
  return acts + wbuf + stats + ints + 256;
}

extern "C" void kernel_launch(void* const* d_in, const int* in_sizes, int n_in,
                              void* d_out, int out_size, void* d_ws, size_t ws_size,
                              hipStream_t stream) {
  const int NA = in_sizes[0] / 64;   // 200000
  const int NM = in_sizes[1] / 32;   // 100000
  const int E  = in_sizes[2] / 2;    // 500000
  if (ws_size < ws_need(NA, NM, E)) return;

  const float* x_acc = (const float*)d_in[0];
  const float* x_mer = (const float*)d_in[1];
  const int* ei_pays = (const int*)d_in[2];
  const int* ei_rev  = (const int*)d_in[3];
  const int* ei_tr   = (const int*)d_in[4];
  const float* pWa = (const float*)d_in[5];
  const float* pba = (const float*)d_in[6];
  const float* pWm = (const float*)d_in[7];
  const float* pbm = (const float*)d_in[8];
  const float* Wl[3]  = {(const float*)d_in[9],  (const float*)d_in[12], (const float*)d_in[15]};
  const float* blp[3] = {(const float*)d_in[10], (const float*)d_in[13], (const float*)d_in[16]};
  const float* Wr[3]  = {(const float*)d_in[11], (const float*)d_in[14], (const float*)d_in[17]};
  const float* bng[3] = {(const float*)d_in[18], (const float*)d_in[20], (const float*)d_in[22]};
  const float* bnb[3] = {(const float*)d_in[19], (const float*)d_in[21], (const float*)d_in[23]};
  const float* cW1 = (const float*)d_in[24];
  const float* cb1 = (const float*)d_in[25];
  const float* cW2 = (const float*)d_in[26];
  const float* cb2 = (const float*)d_in[27];

  char* p = (char*)d_ws;
  ushort_t* A0 = (ushort_t*)p; p += (size_t)NA * 128 * 2;
  ushort_t* A1 = (ushort_t*)p; p += (size_t)NA * 128 * 2;
  ushort_t* M0 = (ushort_t*)p; p += (size_t)NM * 128 * 2;
  ushort_t* M1 = (ushort_t*)p; p += (size_t)NM * 128 * 2;
  ushort_t* WB0 = (ushort_t*)p; p += (size_t)196608 * 2;
  ushort_t* WB1 = (ushort_t*)p; p += (size_t)196608 * 2;
  ushort_t* WB2 = (ushort_t*)p; p += (size_t)98304 * 2;
  ushort_t* WPA = (ushort_t*)p; p += (size_t)16384 * 2;
  ushort_t* WPM = (ushort_t*)p; p += (size_t)8192 * 2;
  ushort_t* WPC = (ushort_t*)p; p += (size_t)8192 * 2;
  p = (char*)(((uintptr_t)p + 15) & ~(uintptr_t)15);
  float* STATS = (float*)p; p += 256 * 4;
  int* rp_p  = (int*)p; p += ((size_t)NM + 1) * 4;
  int* cur_p = (int*)p; p += (size_t)NM * 4;
  int* ci_p  = (int*)p; p += (size_t)E * 4;
  int* rp_r  = (int*)p; p += ((size_t)NA + 1) * 4;
  int* cur_r = (int*)p; p += (size_t)NA * 4;
  int* ci_r  = (int*)p; p += (size_t)E * 4;
  int* rp_t  = (int*)p; p += ((size_t)NA + 1) * 4;
  int* cur_t = (int*)p; p += (size_t)NA * 4;
  int* ci_t  = (int*)p; p += (size_t)E * 4;
  int* bsum  = (int*)p; p += 1024 * 4;

  // ---- CSR builds (cur doubles as count buffer, then cursor) ----
  struct ET { const int* ei; int nd; int* rp; int* cur; int* ci; };
  ET et[3] = {
      {ei_pays, NM, rp_p, cur_p, ci_p},
      {ei_rev,  NA, rp_r, cur_r, ci_r},
      {ei_tr,   NA, rp_t, cur_t, ci_t},
  };
  for (int t = 0; t < 3; ++t) {
    hipMemsetAsync(et[t].cur, 0, (size_t)et[t].nd * sizeof(int), stream);
    cnt_kernel<<<idiv(E, 256), 256, 0, stream>>>(et[t].ei, et[t].cur, E);
    int nb = idiv(et[t].nd, SCAN_EPB);
    bsum_kernel<<<nb, SCAN_TPB, 0, stream>>>(et[t].cur, bsum, et[t].nd);
    bscan_kernel<<<1, 1024, 0, stream>>>(bsum, nb);
    scatter_scan_kernel<<<nb, SCAN_TPB, 0, stream>>>(et[t].cur, bsum, et[t].rp,
                                                     et[t].nd, E);
    fill_kernel<<<idiv(E, 256), 256, 0, stream>>>(et[t].ei, et[t].cur, et[t].ci, E);
  }

  // ---- W conversions ----
  wprep_kernel<<<idiv(3 * 2 * 128 * 128, 256), 256, 0, stream>>>(Wl[0], Wr[0], WB0, 128);
  wprep_kernel<<<idiv(3 * 2 * 128 * 128, 256), 256, 0, stream>>>(Wl[1], Wr[1], WB1, 128);
  wprep_kernel<<<idiv(3 * 2 * 64 * 128, 256), 256, 0, stream>>>(Wl[2], Wr[2], WB2, 64);
  wprep_one_kernel<<<idiv(128 * 64, 256), 256, 0, stream>>>(pWa, WPA, 128, 64);
  wprep_one_kernel<<<idiv(128 * 32, 256), 256, 0, stream>>>(pWm, WPM, 128, 32);
  wprep_one_kernel<<<idiv(64 * 64, 256), 256, 0, stream>>>(cW1, WPC, 64, 64);

  // ---- input projections (MFMA) ----
  proj_mfma_kernel<64><<<idiv(NA, 32), 256, 0, stream>>>(x_acc, WPA, pba, A0, NA);
  proj_mfma_kernel<32><<<idiv(NM, 32), 256, 0, stream>>>(x_mer, WPM, pbm, M0, NM);

  // ---- 3 hetero layers ----
  ushort_t *xa = A0, *xm = M0, *oa = A1, *om = M1;
  run_layer<128, true>(WB0, blp[0], bng[0], bnb[0], xa, xm, oa, om, STATS,
                       rp_p, ci_p, rp_r, ci_r, rp_t, ci_t, NA, NM, stream);
  { ushort_t* t = xa; xa = oa; oa = t; t = xm; xm = om; om = t; }
  run_layer<128, true>(WB1, blp[1], bng[1], bnb[1], xa, xm, oa, om, STATS,
                       rp_p, ci_p, rp_r, ci_r, rp_t, ci_t, NA, NM, stream);
  { ushort_t* t = xa; xa = oa; oa = t; t = xm; xm = om; om = t; }
  run_layer<64, false>(WB2, blp[2], bng[2], bnb[2], xa, xm, oa, om, STATS,
                       rp_p, ci_p, rp_r, ci_r, rp_t, ci_t, NA, NM, stream);
  { ushort_t* t = xa; xa = oa; oa = t; t = xm; xm = om; om = t; }

  // ---- classifier head on accounts (MFMA) ----
  clf_mfma_kernel<<<idiv(NA, 32), 256, 0, stream>>>(xa, WPC, cb1, cW2, cb2,
                                                    (float*)d_out, NA);
}